// Round 8
// baseline (315.765 us; speedup 1.0000x reference)
//
#include <hip/hip_runtime.h>
#include <math.h>

#define NB   4
#define IH   128
#define IW   128
#define NTOK 16384        // IH*IW
#define CC   96
#define HID  192
#define QKD  48
#define EPSF 1e-5f
#define INV_N (1.0f/16384.0f)

typedef __attribute__((ext_vector_type(8))) short sh8;    // 8 bf16 (4 VGPRs)
typedef __attribute__((ext_vector_type(4))) float f32x4;  // 4 fp32

__device__ __forceinline__ float wave_sum64(float v){
    #pragma unroll
    for (int off = 32; off > 0; off >>= 1) v += __shfl_xor(v, off, 64);
    return v;
}
__device__ __forceinline__ float siluf(float x){ return x / (1.0f + __expf(-x)); }
__device__ __forceinline__ float geluf(float x){ return 0.5f*x*(1.0f + erff(x*0.7071067811865475f)); }

__device__ __forceinline__ unsigned short f2bf(float f){   // RNE float->bf16 bits
    union { float f; unsigned u; } x; x.f = f;
    unsigned u = x.u + 0x7FFFu + ((x.u >> 16) & 1u);
    return (unsigned short)(u >> 16);
}
__device__ __forceinline__ unsigned pack2(float a, float b){
    return (unsigned)f2bf(a) | ((unsigned)f2bf(b) << 16);
}

// ---------------- 1. LayerNorm over C=96, wave per row ----------------
__global__ __launch_bounds__(256) void k_ln(const float* __restrict__ x,
                                            const float* __restrict__ w,
                                            const float* __restrict__ bb,
                                            float* __restrict__ nx){
    int row = blockIdx.x*4 + (threadIdx.x >> 6);
    int l = threadIdx.x & 63;
    const float* xr = x + (size_t)row*CC;
    float a = xr[l];
    float b = (l < 32) ? xr[64+l] : 0.0f;
    float s = wave_sum64(a + b);
    float m = s * (1.0f/96.0f);
    float d1 = a - m;
    float d2 = b - m;
    float sq = d1*d1 + ((l < 32) ? d2*d2 : 0.0f);
    float var = wave_sum64(sq) * (1.0f/96.0f);
    float rstd = rsqrtf(var + EPSF);
    float* o = nx + (size_t)row*CC;
    o[l] = d1*rstd*w[l] + bb[l];
    if (l < 32) o[64+l] = d2*rstd*w[64+l] + bb[64+l];
}

// ---------------- 2. h = silu(nx @ Wh + bh) via bf16 MFMA; split v/gate ----------------
__global__ __launch_bounds__(256) void k_hgemm(const float* __restrict__ nx,
                                               const float* __restrict__ Wh,
                                               const float* __restrict__ bh,
                                               float* __restrict__ vbuf,
                                               float* __restrict__ gate){
    __shared__ unsigned short whbf[192*100];   // [col][k] bf16, stride 100
    int tid  = threadIdx.x;
    int lane = tid & 63;
    int wid  = tid >> 6;
    int lo   = lane & 15;
    int g    = lane >> 4;
    int row0 = blockIdx.x*64 + wid*16;

    // stage Wh (96x192 fp32, row-major [k][col]) -> whbf[col][k]
    #pragma unroll
    for (int it = 0; it < 72; it++){
        int idx = tid + it*256;          // 0..18431
        int k = idx / 192, col = idx - k*192;
        whbf[col*100 + k] = f2bf(Wh[idx]);
    }

    // A-fragments: lane holds nx[row0+lo][kc*32 + g*8 .. +7]
    sh8 a[3];
    {
        const float* ar = nx + (size_t)(row0 + lo)*CC;
        #pragma unroll
        for (int kc = 0; kc < 3; kc++){
            f32x4 x0 = *(const f32x4*)(ar + kc*32 + g*8);
            f32x4 x1 = *(const f32x4*)(ar + kc*32 + g*8 + 4);
            union { unsigned u[4]; sh8 v; } pk;
            pk.u[0] = pack2(x0[0], x0[1]); pk.u[1] = pack2(x0[2], x0[3]);
            pk.u[2] = pack2(x1[0], x1[1]); pk.u[3] = pack2(x1[2], x1[3]);
            a[kc] = pk.v;
        }
    }
    __syncthreads();

    f32x4 acc[12];
    #pragma unroll
    for (int ct = 0; ct < 12; ct++) acc[ct] = (f32x4){0.f,0.f,0.f,0.f};
    #pragma unroll
    for (int ct = 0; ct < 12; ct++){
        #pragma unroll
        for (int kc = 0; kc < 3; kc++){
            sh8 bw = *(const sh8*)&whbf[(ct*16 + lo)*100 + kc*32 + g*8];
            acc[ct] = __builtin_amdgcn_mfma_f32_16x16x32_bf16(a[kc], bw, acc[ct], 0, 0, 0);
        }
    }

    // epilogue: silu(+bias), split v/gate. row = row0+g*4+j, col = ct*16+lo
    #pragma unroll
    for (int ct = 0; ct < 12; ct++){
        int col = ct*16 + lo;
        float bcol = bh[col];
        #pragma unroll
        for (int j = 0; j < 4; j++){
            size_t row = row0 + g*4 + j;
            float hv = siluf(acc[ct][j] + bcol);
            if (col < 96) vbuf[row*CC + col] = hv;
            else          gate[row*CC + col - 96] = hv;
        }
    }
}

// ---------------- 3. conv (patch GEMM, K-split) ----------------
__global__ __launch_bounds__(256) void k_conv(const float* __restrict__ nx,
                                              const float* __restrict__ wconv,
                                              float* __restrict__ part,
                                              int posLog, int pdimLog, int pszLog, int kTotal){
    __shared__ float pt[64*96];
    __shared__ float wt[96*100];
    int posPerImg = 1 << posLog;
    int pdim = 1 << pdimLog;
    int psz  = 1 << pszLog;
    int ksLog = 2*pszLog;
    int rowblocks = (NB << posLog) >> 6;
    int rb = blockIdx.x % rowblocks;
    int split = blockIdx.x / rowblocks;
    int tid = threadIdx.x;
    int to = tid & 15, ty = tid >> 4;
    float acc[4][6];
    #pragma unroll
    for (int i = 0; i < 4; i++)
        #pragma unroll
        for (int j = 0; j < 6; j++) acc[i][j] = 0.0f;

    for (int half = 0; half < 2; half++){
        int kb = split*192 + half*96;
        __syncthreads();
        for (int idx = tid; idx < 96*96; idx += 256){
            int o = idx / 96, kk = idx % 96;
            wt[o*100 + kk] = wconv[(size_t)o*kTotal + kb + kk];
        }
        for (int idx = tid; idx < 64*96; idx += 256){
            int r = idx / 96, kk = idx % 96;
            int R = rb*64 + r;
            int b = R >> posLog, p = R & (posPerImg-1);
            int k = kb + kk;
            int c = k >> ksLog, s = k & ((psz*psz)-1);
            int pi = p >> pdimLog, pj = p & (pdim-1);
            int px = (pi << pszLog) + (s >> pszLog);
            int py = (pj << pszLog) + (s & (psz-1));
            pt[r*96 + kk] = nx[((size_t)b*NTOK + px*IW + py)*CC + c];
        }
        __syncthreads();
        #pragma unroll 4
        for (int k4 = 0; k4 < 24; k4++){
            float4 xa[4], wb[6];
            #pragma unroll
            for (int i = 0; i < 4; i++)
                xa[i] = *(const float4*)&pt[(ty*4+i)*96 + k4*4];
            #pragma unroll
            for (int j = 0; j < 6; j++)
                wb[j] = *(const float4*)&wt[(to + j*16)*100 + k4*4];
            #pragma unroll
            for (int i = 0; i < 4; i++)
                #pragma unroll
                for (int j = 0; j < 6; j++){
                    acc[i][j] += xa[i].x*wb[j].x + xa[i].y*wb[j].y
                               + xa[i].z*wb[j].z + xa[i].w*wb[j].w;
                }
        }
    }
    int rowsTotal = NB << posLog;
    #pragma unroll
    for (int i = 0; i < 4; i++){
        int R = rb*64 + ty*4 + i;
        #pragma unroll
        for (int j = 0; j < 6; j++){
            int o = to + j*16;
            part[((size_t)split*rowsTotal + R)*96 + o] = acc[i][j];
        }
    }
}

// ---------------- 4. reduce K-splits + bias + LN + gelu + Z/q/k -> bf16 qp/ktp ----------------
// qp[b][m][64] bf16 (d padded 48..63 = 0); ktp[b][d][m] bf16 (pre-transposed for attn gemm2).
__global__ __launch_bounds__(64) void k_reduce(const float* __restrict__ part,
                                               int nsplit, int rows, int Mper,
                                               const float* __restrict__ cbias,
                                               const float* __restrict__ lw,
                                               const float* __restrict__ lb,
                                               const float* __restrict__ wqk,
                                               const float* __restrict__ bqk,
                                               const float* __restrict__ g,
                                               const float* __restrict__ be,
                                               unsigned short* __restrict__ qp,
                                               unsigned short* __restrict__ ktp){
    __shared__ float xsh[96];
    int row = blockIdx.x;
    int l = threadIdx.x;
    float y1 = 0.0f, y2 = 0.0f;
    for (int s = 0; s < nsplit; s++){
        const float* pr = part + ((size_t)s*rows + row)*96;
        y1 += pr[l];
        if (l < 32) y2 += pr[64+l];
    }
    y1 += cbias[l];
    if (l < 32) y2 += cbias[64+l];
    float s = wave_sum64(y1 + ((l < 32) ? y2 : 0.0f));
    float m = s * (1.0f/96.0f);
    float d1 = y1 - m, d2 = y2 - m;
    float var = wave_sum64(d1*d1 + ((l < 32) ? d2*d2 : 0.0f)) * (1.0f/96.0f);
    float rstd = rsqrtf(var + EPSF);
    xsh[l] = geluf(d1*rstd*lw[l] + lb[l]);
    if (l < 32) xsh[64+l] = geluf(d2*rstd*lw[64+l] + lb[64+l]);
    __syncthreads();
    if (l < 48){
        float z = bqk[l];
        #pragma unroll 4
        for (int c = 0; c < 96; c++) z += xsh[c]*wqk[c*48 + l];
        z = siluf(z);
        float qv = z*g[l]    + be[l];
        float kv = z*g[48+l] + be[48+l];
        int b = row / Mper, p = row - b*Mper;
        qp[(size_t)row*64 + l] = f2bf(qv);
        ktp[((size_t)b*48 + l)*Mper + p] = f2bf(kv);
    } else {
        qp[(size_t)row*64 + l] = 0;      // zero the d-pad
    }
}

// ---------------- 5. attention via bf16 MFMA, B-frags direct from global (L2) ----------------
// Block = 64 rows (4 waves x 16). No q/k LDS, no barriers in loop; only wave-private P tile.
__global__ __launch_bounds__(256) void k_attn(const float* __restrict__ vbuf,
                                              const unsigned short* __restrict__ qp1,
                                              const unsigned short* __restrict__ ktp1,
                                              const unsigned short* __restrict__ qp2,
                                              const unsigned short* __restrict__ ktp2,
                                              float* __restrict__ V1,
                                              float* __restrict__ V2){
    __shared__ float Pl[4][16*36];          // per-wave P tile [16n][32m] (stride 36)

    int bx   = blockIdx.x;
    int kind = bx >> 10;                 // 0: branch1 (M=256), 1: branch2 (M=1024)
    int blk  = bx & 1023;
    int tid  = threadIdx.x;
    int wid  = tid >> 6;
    int lane = tid & 63;
    int lo   = lane & 15;
    int g    = lane >> 4;
    int row0 = blk*64 + wid*16;          // wave's first global row (0..65535)
    int b    = row0 >> 14;               // batch

    int   M    = kind ? 1024 : 256;
    const unsigned short* qp = (kind ? qp2 : qp1) + (size_t)b*M*64;
    const unsigned short* kt = (kind ? ktp2 : ktp1) + (size_t)b*48*M;
    int   voff = kind ? 48 : 0;
    float* vout = kind ? V2 : V1;

    // v A-fragments (per-wave resident): lane holds v[row0+lo][d], d = kc*32 + g*8 .. +7
    sh8 va[2];
    {
        const float* vrow = vbuf + (size_t)(row0 + lo)*CC + voff;
        union { unsigned u[4]; sh8 v; } pk;
        f32x4 a0 = *(const f32x4*)(vrow + g*8);
        f32x4 a1 = *(const f32x4*)(vrow + g*8 + 4);
        pk.u[0] = pack2(a0[0], a0[1]); pk.u[1] = pack2(a0[2], a0[3]);
        pk.u[2] = pack2(a1[0], a1[1]); pk.u[3] = pack2(a1[2], a1[3]);
        va[0] = pk.v;
        if (g < 2){
            f32x4 b0 = *(const f32x4*)(vrow + 32 + g*8);
            f32x4 b1 = *(const f32x4*)(vrow + 32 + g*8 + 4);
            pk.u[0] = pack2(b0[0], b0[1]); pk.u[1] = pack2(b0[2], b0[3]);
            pk.u[2] = pack2(b1[0], b1[1]); pk.u[3] = pack2(b1[2], b1[3]);
        } else {
            pk.u[0] = 0u; pk.u[1] = 0u; pk.u[2] = 0u; pk.u[3] = 0u;
        }
        va[1] = pk.v;
    }

    f32x4 acc[3];
    acc[0] = (f32x4){0.f,0.f,0.f,0.f};
    acc[1] = (f32x4){0.f,0.f,0.f,0.f};
    acc[2] = (f32x4){0.f,0.f,0.f,0.f};
    float* Pw = Pl[wid];

    for (int mb = 0; mb < M; mb += 32){
        // ---- GEMM1 + relu^2 -> P (wave-private; same-wave lgkmcnt ordering) ----
        #pragma unroll
        for (int mt = 0; mt < 2; mt++){
            f32x4 c = (f32x4){0.f,0.f,0.f,0.f};
            #pragma unroll
            for (int kc = 0; kc < 2; kc++){
                sh8 bq = *(const sh8*)&qp[(size_t)(mb + mt*16 + lo)*64 + kc*32 + g*8];
                c = __builtin_amdgcn_mfma_f32_16x16x32_bf16(va[kc], bq, c, 0, 0, 0);
            }
            #pragma unroll
            for (int j = 0; j < 4; j++){
                float s = c[j] * INV_N;
                s = fmaxf(s, 0.f);
                Pw[(g*4 + j)*36 + mt*16 + lo] = s*s;
            }
        }

        // ---- pa from P tile ----
        sh8 pa;
        {
            f32x4 p0 = *(const f32x4*)&Pw[lo*36 + g*8];
            f32x4 p1 = *(const f32x4*)&Pw[lo*36 + g*8 + 4];
            union { unsigned u[4]; sh8 v; } pk;
            pk.u[0] = pack2(p0[0], p0[1]); pk.u[1] = pack2(p0[2], p0[3]);
            pk.u[2] = pack2(p1[0], p1[1]); pk.u[3] = pack2(p1[2], p1[3]);
            pa = pk.v;
        }

        // ---- GEMM2: acc += P . k ----
        #pragma unroll
        for (int dt = 0; dt < 3; dt++){
            sh8 bk = *(const sh8*)&kt[(size_t)(dt*16 + lo)*M + mb + g*8];
            acc[dt] = __builtin_amdgcn_mfma_f32_16x16x32_bf16(pa, bk, acc[dt], 0, 0, 0);
        }
    }

    // ---- write O: row = row0 + g*4 + j, col = dt*16 + lo ----
    #pragma unroll
    for (int dt = 0; dt < 3; dt++)
        #pragma unroll
        for (int j = 0; j < 4; j++)
            vout[(size_t)(row0 + g*4 + j)*48 + dt*16 + lo] = acc[dt][j];
}

// ---------------- 6. final via bf16 MFMA: out = (xc*gate)@proj + projb + xc ----------------
__global__ __launch_bounds__(256) void k_final(const float* __restrict__ V1,
                                               const float* __restrict__ V2,
                                               const float* __restrict__ gate,
                                               const float* __restrict__ projw,
                                               const float* __restrict__ projb,
                                               float* __restrict__ out){
    __shared__ unsigned short pjbf[96*100];    // [col][k] bf16, stride 100
    int tid  = threadIdx.x;
    int lane = tid & 63;
    int wid  = tid >> 6;
    int lo   = lane & 15;
    int g    = lane >> 4;
    int row0 = blockIdx.x*64 + wid*16;

    // stage proj_w (96x96 fp32, row-major [k][col]) -> pjbf[col][k]
    #pragma unroll
    for (int it = 0; it < 36; it++){
        int idx = tid + it*256;          // 0..9215
        int k = idx / 96, col = idx - k*96;
        pjbf[col*100 + k] = f2bf(projw[idx]);
    }

    // A-fragments: lane holds value[row0+lo][kc*32+g*8 .. +7], value = xc*gate
    sh8 a[3];
    {
        size_t row = row0 + lo;
        const float* gr = gate + row*CC;
        #pragma unroll
        for (int kc = 0; kc < 3; kc++){
            int d0 = kc*32 + g*8;
            const float* xsrc = (d0 < 48) ? (V1 + row*48 + d0) : (V2 + row*48 + d0 - 48);
            f32x4 x0 = *(const f32x4*)xsrc;
            f32x4 x1 = *(const f32x4*)(xsrc + 4);
            f32x4 g0 = *(const f32x4*)(gr + d0);
            f32x4 g1 = *(const f32x4*)(gr + d0 + 4);
            union { unsigned u[4]; sh8 v; } pk;
            pk.u[0] = pack2(x0[0]*g0[0], x0[1]*g0[1]);
            pk.u[1] = pack2(x0[2]*g0[2], x0[3]*g0[3]);
            pk.u[2] = pack2(x1[0]*g1[0], x1[1]*g1[1]);
            pk.u[3] = pack2(x1[2]*g1[2], x1[3]*g1[3]);
            a[kc] = pk.v;
        }
    }
    __syncthreads();

    f32x4 acc[6];
    #pragma unroll
    for (int ct = 0; ct < 6; ct++) acc[ct] = (f32x4){0.f,0.f,0.f,0.f};
    #pragma unroll
    for (int ct = 0; ct < 6; ct++){
        #pragma unroll
        for (int kc = 0; kc < 3; kc++){
            sh8 bw = *(const sh8*)&pjbf[(ct*16 + lo)*100 + kc*32 + g*8];
            acc[ct] = __builtin_amdgcn_mfma_f32_16x16x32_bf16(a[kc], bw, acc[ct], 0, 0, 0);
        }
    }

    // epilogue: out[row][col] = acc + projb[col] + xc[row][col]
    #pragma unroll
    for (int ct = 0; ct < 6; ct++){
        int col = ct*16 + lo;
        float bcol = projb[col];
        const float* xsrc = (ct < 3) ? (V1 + col) : (V2 + col - 48);
        #pragma unroll
        for (int j = 0; j < 4; j++){
            size_t row = row0 + g*4 + j;
            float xc = xsrc[row*48];
            out[row*CC + col] = acc[ct][j] + bcol + xc;
        }
    }
}

extern "C" void kernel_launch(void* const* d_in, const int* in_sizes, int n_in,
                              void* d_out, int out_size, void* d_ws, size_t ws_size,
                              hipStream_t stream){
    const float* x      = (const float*)d_in[0];
    const float* norm_w = (const float*)d_in[3];
    const float* norm_b = (const float*)d_in[4];
    const float* Wh     = (const float*)d_in[5];
    const float* bh     = (const float*)d_in[6];
    const float* Wqk    = (const float*)d_in[7];
    const float* bqk    = (const float*)d_in[8];
    const float* g1     = (const float*)d_in[9];
    const float* be1    = (const float*)d_in[10];
    const float* g2     = (const float*)d_in[11];
    const float* be2    = (const float*)d_in[12];
    const float* sr1_w  = (const float*)d_in[13];
    const float* sr1_b  = (const float*)d_in[14];
    const float* sr2_w  = (const float*)d_in[15];
    const float* sr2_b  = (const float*)d_in[16];
    const float* n1_w   = (const float*)d_in[17];
    const float* n1_b   = (const float*)d_in[18];
    const float* n2_w   = (const float*)d_in[19];
    const float* n2_b   = (const float*)d_in[20];
    const float* proj_w = (const float*)d_in[21];
    const float* proj_b = (const float*)d_in[22];
    float* out = (float*)d_out;

    float* ws = (float*)d_ws;
    size_t off = 0;
    float* nx   = ws + off; off += (size_t)NB*NTOK*CC;
    float* vbuf = ws + off; off += (size_t)NB*NTOK*CC;
    float* gate = ws + off; off += (size_t)NB*NTOK*CC;
    unsigned short* qp1 = (unsigned short*)(ws + off); off += (size_t)NB*256*64/2;
    unsigned short* kt1 = (unsigned short*)(ws + off); off += (size_t)NB*48*256/2;
    unsigned short* qp2 = (unsigned short*)(ws + off); off += (size_t)NB*1024*64/2;
    unsigned short* kt2 = (unsigned short*)(ws + off); off += (size_t)NB*48*1024/2;
    float* part1= ws + off; off += (size_t)32*NB*256*96;
    float* part2= ws + off; off += (size_t)8*NB*1024*96;
    float* V1   = ws + off; off += (size_t)NB*NTOK*48;
    float* V2   = ws + off; off += (size_t)NB*NTOK*48;
    if (ws_size < off*sizeof(float)) return;

    k_ln   <<<16384, 256, 0, stream>>>(x, norm_w, norm_b, nx);
    k_hgemm<<<1024, 256, 0, stream>>>(nx, Wh, bh, vbuf, gate);
    k_conv <<<512, 256, 0, stream>>>(nx, sr1_w, part1, 8, 4, 3, 6144);
    k_conv <<<512, 256, 0, stream>>>(nx, sr2_w, part2, 10, 5, 2, 1536);
    k_reduce<<<1024, 64, 0, stream>>>(part1, 32, 1024, 256, sr1_b, n1_w, n1_b, Wqk, bqk, g1, be1, qp1, kt1);
    k_reduce<<<4096, 64, 0, stream>>>(part2, 8, 4096, 1024, sr2_b, n2_w, n2_b, Wqk, bqk, g2, be2, qp2, kt2);
    k_attn <<<2048, 256, 0, stream>>>(vbuf, qp1, kt1, qp2, kt2, V1, V2);
    k_final<<<1024, 256, 0, stream>>>(V1, V2, gate, proj_w, proj_b, out);
}

// Round 9
// 210.881 us; speedup vs baseline: 1.4974x; 1.4974x over previous
//
#include <hip/hip_runtime.h>
#include <math.h>

#define NB   4
#define IH   128
#define IW   128
#define NTOK 16384        // IH*IW
#define CC   96
#define HID  192
#define QKD  48
#define EPSF 1e-5f
#define INV_N (1.0f/16384.0f)

typedef __attribute__((ext_vector_type(8))) short sh8;    // 8 bf16 (4 VGPRs)
typedef __attribute__((ext_vector_type(4))) float f32x4;  // 4 fp32

__device__ __forceinline__ float wave_sum64(float v){
    #pragma unroll
    for (int off = 32; off > 0; off >>= 1) v += __shfl_xor(v, off, 64);
    return v;
}
__device__ __forceinline__ float siluf(float x){ return x / (1.0f + __expf(-x)); }
__device__ __forceinline__ float geluf(float x){ return 0.5f*x*(1.0f + erff(x*0.7071067811865475f)); }

__device__ __forceinline__ unsigned short f2bf(float f){   // RNE float->bf16 bits
    union { float f; unsigned u; } x; x.f = f;
    unsigned u = x.u + 0x7FFFu + ((x.u >> 16) & 1u);
    return (unsigned short)(u >> 16);
}
__device__ __forceinline__ unsigned pack2(float a, float b){
    return (unsigned)f2bf(a) | ((unsigned)f2bf(b) << 16);
}

// ---------------- 1. LayerNorm over C=96, wave per row ----------------
__global__ __launch_bounds__(256) void k_ln(const float* __restrict__ x,
                                            const float* __restrict__ w,
                                            const float* __restrict__ bb,
                                            float* __restrict__ nx){
    int row = blockIdx.x*4 + (threadIdx.x >> 6);
    int l = threadIdx.x & 63;
    const float* xr = x + (size_t)row*CC;
    float a = xr[l];
    float b = (l < 32) ? xr[64+l] : 0.0f;
    float s = wave_sum64(a + b);
    float m = s * (1.0f/96.0f);
    float d1 = a - m;
    float d2 = b - m;
    float sq = d1*d1 + ((l < 32) ? d2*d2 : 0.0f);
    float var = wave_sum64(sq) * (1.0f/96.0f);
    float rstd = rsqrtf(var + EPSF);
    float* o = nx + (size_t)row*CC;
    o[l] = d1*rstd*w[l] + bb[l];
    if (l < 32) o[64+l] = d2*rstd*w[64+l] + bb[64+l];
}

// ---------------- 2. h = silu(nx @ Wh + bh) via bf16 MFMA; split v/gate ----------------
__global__ __launch_bounds__(256) void k_hgemm(const float* __restrict__ nx,
                                               const float* __restrict__ Wh,
                                               const float* __restrict__ bh,
                                               float* __restrict__ vbuf,
                                               float* __restrict__ gate){
    __shared__ unsigned short whbf[192*100];   // [col][k] bf16, stride 100
    int tid  = threadIdx.x;
    int lane = tid & 63;
    int wid  = tid >> 6;
    int lo   = lane & 15;
    int g    = lane >> 4;
    int row0 = blockIdx.x*64 + wid*16;

    // stage Wh (96x192 fp32, row-major [k][col]) -> whbf[col][k]
    #pragma unroll
    for (int it = 0; it < 72; it++){
        int idx = tid + it*256;          // 0..18431
        int k = idx / 192, col = idx - k*192;
        whbf[col*100 + k] = f2bf(Wh[idx]);
    }

    // A-fragments: lane holds nx[row0+lo][kc*32 + g*8 .. +7]
    sh8 a[3];
    {
        const float* ar = nx + (size_t)(row0 + lo)*CC;
        #pragma unroll
        for (int kc = 0; kc < 3; kc++){
            f32x4 x0 = *(const f32x4*)(ar + kc*32 + g*8);
            f32x4 x1 = *(const f32x4*)(ar + kc*32 + g*8 + 4);
            union { unsigned u[4]; sh8 v; } pk;
            pk.u[0] = pack2(x0[0], x0[1]); pk.u[1] = pack2(x0[2], x0[3]);
            pk.u[2] = pack2(x1[0], x1[1]); pk.u[3] = pack2(x1[2], x1[3]);
            a[kc] = pk.v;
        }
    }
    __syncthreads();

    f32x4 acc[12];
    #pragma unroll
    for (int ct = 0; ct < 12; ct++) acc[ct] = (f32x4){0.f,0.f,0.f,0.f};
    #pragma unroll
    for (int ct = 0; ct < 12; ct++){
        #pragma unroll
        for (int kc = 0; kc < 3; kc++){
            sh8 bw = *(const sh8*)&whbf[(ct*16 + lo)*100 + kc*32 + g*8];
            acc[ct] = __builtin_amdgcn_mfma_f32_16x16x32_bf16(a[kc], bw, acc[ct], 0, 0, 0);
        }
    }

    // epilogue: silu(+bias), split v/gate. row = row0+g*4+j, col = ct*16+lo
    #pragma unroll
    for (int ct = 0; ct < 12; ct++){
        int col = ct*16 + lo;
        float bcol = bh[col];
        #pragma unroll
        for (int j = 0; j < 4; j++){
            size_t row = row0 + g*4 + j;
            float hv = siluf(acc[ct][j] + bcol);
            if (col < 96) vbuf[row*CC + col] = hv;
            else          gate[row*CC + col - 96] = hv;
        }
    }
}

// ---------------- 3. conv (patch GEMM, K-split) ----------------
__global__ __launch_bounds__(256) void k_conv(const float* __restrict__ nx,
                                              const float* __restrict__ wconv,
                                              float* __restrict__ part,
                                              int posLog, int pdimLog, int pszLog, int kTotal){
    __shared__ float pt[64*96];
    __shared__ float wt[96*100];
    int posPerImg = 1 << posLog;
    int pdim = 1 << pdimLog;
    int psz  = 1 << pszLog;
    int ksLog = 2*pszLog;
    int rowblocks = (NB << posLog) >> 6;
    int rb = blockIdx.x % rowblocks;
    int split = blockIdx.x / rowblocks;
    int tid = threadIdx.x;
    int to = tid & 15, ty = tid >> 4;
    float acc[4][6];
    #pragma unroll
    for (int i = 0; i < 4; i++)
        #pragma unroll
        for (int j = 0; j < 6; j++) acc[i][j] = 0.0f;

    for (int half = 0; half < 2; half++){
        int kb = split*192 + half*96;
        __syncthreads();
        for (int idx = tid; idx < 96*96; idx += 256){
            int o = idx / 96, kk = idx % 96;
            wt[o*100 + kk] = wconv[(size_t)o*kTotal + kb + kk];
        }
        for (int idx = tid; idx < 64*96; idx += 256){
            int r = idx / 96, kk = idx % 96;
            int R = rb*64 + r;
            int b = R >> posLog, p = R & (posPerImg-1);
            int k = kb + kk;
            int c = k >> ksLog, s = k & ((psz*psz)-1);
            int pi = p >> pdimLog, pj = p & (pdim-1);
            int px = (pi << pszLog) + (s >> pszLog);
            int py = (pj << pszLog) + (s & (psz-1));
            pt[r*96 + kk] = nx[((size_t)b*NTOK + px*IW + py)*CC + c];
        }
        __syncthreads();
        #pragma unroll 4
        for (int k4 = 0; k4 < 24; k4++){
            float4 xa[4], wb[6];
            #pragma unroll
            for (int i = 0; i < 4; i++)
                xa[i] = *(const float4*)&pt[(ty*4+i)*96 + k4*4];
            #pragma unroll
            for (int j = 0; j < 6; j++)
                wb[j] = *(const float4*)&wt[(to + j*16)*100 + k4*4];
            #pragma unroll
            for (int i = 0; i < 4; i++)
                #pragma unroll
                for (int j = 0; j < 6; j++){
                    acc[i][j] += xa[i].x*wb[j].x + xa[i].y*wb[j].y
                               + xa[i].z*wb[j].z + xa[i].w*wb[j].w;
                }
        }
    }
    int rowsTotal = NB << posLog;
    #pragma unroll
    for (int i = 0; i < 4; i++){
        int R = rb*64 + ty*4 + i;
        #pragma unroll
        for (int j = 0; j < 6; j++){
            int o = to + j*16;
            part[((size_t)split*rowsTotal + R)*96 + o] = acc[i][j];
        }
    }
}

// ---------------- 4. reduce K-splits + bias + LN + gelu + Z/q/k -> bf16 qp/ktp ----------------
// qp[b][m][64] bf16 (d padded 48..63 = 0); ktp[b][d][m] bf16 (pre-transposed for attn gemm2).
__global__ __launch_bounds__(64) void k_reduce(const float* __restrict__ part,
                                               int nsplit, int rows, int Mper,
                                               const float* __restrict__ cbias,
                                               const float* __restrict__ lw,
                                               const float* __restrict__ lb,
                                               const float* __restrict__ wqk,
                                               const float* __restrict__ bqk,
                                               const float* __restrict__ g,
                                               const float* __restrict__ be,
                                               unsigned short* __restrict__ qp,
                                               unsigned short* __restrict__ ktp){
    __shared__ float xsh[96];
    int row = blockIdx.x;
    int l = threadIdx.x;
    float y1 = 0.0f, y2 = 0.0f;
    for (int s = 0; s < nsplit; s++){
        const float* pr = part + ((size_t)s*rows + row)*96;
        y1 += pr[l];
        if (l < 32) y2 += pr[64+l];
    }
    y1 += cbias[l];
    if (l < 32) y2 += cbias[64+l];
    float s = wave_sum64(y1 + ((l < 32) ? y2 : 0.0f));
    float m = s * (1.0f/96.0f);
    float d1 = y1 - m, d2 = y2 - m;
    float var = wave_sum64(d1*d1 + ((l < 32) ? d2*d2 : 0.0f)) * (1.0f/96.0f);
    float rstd = rsqrtf(var + EPSF);
    xsh[l] = geluf(d1*rstd*lw[l] + lb[l]);
    if (l < 32) xsh[64+l] = geluf(d2*rstd*lw[64+l] + lb[64+l]);
    __syncthreads();
    if (l < 48){
        float z = bqk[l];
        #pragma unroll 4
        for (int c = 0; c < 96; c++) z += xsh[c]*wqk[c*48 + l];
        z = siluf(z);
        float qv = z*g[l]    + be[l];
        float kv = z*g[48+l] + be[48+l];
        int b = row / Mper, p = row - b*Mper;
        qp[(size_t)row*64 + l] = f2bf(qv);
        ktp[((size_t)b*48 + l)*Mper + p] = f2bf(kv);
    } else {
        qp[(size_t)row*64 + l] = 0;      // zero the d-pad
    }
}

// ---------------- 5. attention via bf16 MFMA, LDS-staged bf16 with async prefetch ----------------
// Block = 64 rows (4 waves x 16). Per 32-m chunk: pure memcpy staging (qp pre-padded,
// ktp pre-transposed, both bf16) + register prefetch of chunk ch+1 issued under compute.
__global__ __launch_bounds__(256) void k_attn(const float* __restrict__ vbuf,
                                              const unsigned short* __restrict__ qp1,
                                              const unsigned short* __restrict__ ktp1,
                                              const unsigned short* __restrict__ qp2,
                                              const unsigned short* __restrict__ ktp2,
                                              float* __restrict__ V1,
                                              float* __restrict__ V2){
    __shared__ unsigned short qs[32*72];    // q[m][d] chunk, stride 72 (144B, 16B-aligned)
    __shared__ unsigned short ks[48*40];    // kT[d][m] chunk, stride 40 (80B, 16B-aligned)
    __shared__ float Pl[4][16*36];          // per-wave P tile [16n][32m]

    int bx   = blockIdx.x;
    int kind = bx >> 10;                 // 0: branch1 (M=256), 1: branch2 (M=1024)
    int blk  = bx & 1023;
    int tid  = threadIdx.x;
    int wid  = tid >> 6;
    int lane = tid & 63;
    int lo   = lane & 15;
    int g    = lane >> 4;
    int row0 = blk*64 + wid*16;          // wave's first global row (0..65535)
    int b    = row0 >> 14;               // batch

    int   M    = kind ? 1024 : 256;
    const unsigned short* qp = (kind ? qp2 : qp1) + (size_t)b*M*64;
    const unsigned short* kt = (kind ? ktp2 : ktp1) + (size_t)b*48*M;
    int   voff = kind ? 48 : 0;
    float* vout = kind ? V2 : V1;

    // v A-fragments (per-wave resident)
    sh8 va[2];
    {
        const float* vrow = vbuf + (size_t)(row0 + lo)*CC + voff;
        union { unsigned u[4]; sh8 v; } pk;
        f32x4 a0 = *(const f32x4*)(vrow + g*8);
        f32x4 a1 = *(const f32x4*)(vrow + g*8 + 4);
        pk.u[0] = pack2(a0[0], a0[1]); pk.u[1] = pack2(a0[2], a0[3]);
        pk.u[2] = pack2(a1[0], a1[1]); pk.u[3] = pack2(a1[2], a1[3]);
        va[0] = pk.v;
        if (g < 2){
            f32x4 b0 = *(const f32x4*)(vrow + 32 + g*8);
            f32x4 b1 = *(const f32x4*)(vrow + 32 + g*8 + 4);
            pk.u[0] = pack2(b0[0], b0[1]); pk.u[1] = pack2(b0[2], b0[3]);
            pk.u[2] = pack2(b1[0], b1[1]); pk.u[3] = pack2(b1[2], b1[3]);
        } else {
            pk.u[0] = 0u; pk.u[1] = 0u; pk.u[2] = 0u; pk.u[3] = 0u;
        }
        va[1] = pk.v;
    }

    // staging thread mapping (constant): q: 256 thr x 16B (row qm, seg qj); k: 192 thr x 16B
    int qm = tid >> 3, qj = tid & 7;
    int kd = tid >> 2, kj = tid & 3;
    bool kact = tid < 192;

    f32x4 acc[3];
    acc[0] = (f32x4){0.f,0.f,0.f,0.f};
    acc[1] = (f32x4){0.f,0.f,0.f,0.f};
    acc[2] = (f32x4){0.f,0.f,0.f,0.f};
    float* Pw = Pl[wid];
    int nchunk = M >> 5;

    // prologue: prefetch chunk 0 into registers
    sh8 qreg = *(const sh8*)(qp + (size_t)qm*64 + qj*8);
    sh8 kreg;
    if (kact) kreg = *(const sh8*)(kt + (size_t)kd*M + kj*8);

    for (int ch = 0; ch < nchunk; ch++){
        int mb = ch*32;
        __syncthreads();                 // previous compute done (WAR on qs/ks)
        *(sh8*)&qs[qm*72 + qj*8] = qreg;
        if (kact) *(sh8*)&ks[kd*40 + kj*8] = kreg;
        if (ch + 1 < nchunk){            // issue next chunk's loads; latency hides under compute
            int mb2 = mb + 32;
            qreg = *(const sh8*)(qp + (size_t)(mb2 + qm)*64 + qj*8);
            if (kact) kreg = *(const sh8*)(kt + (size_t)kd*M + mb2 + kj*8);
        }
        __syncthreads();                 // staging visible

        // ---- GEMM1 + relu^2 -> P ----
        #pragma unroll
        for (int mt = 0; mt < 2; mt++){
            f32x4 c = (f32x4){0.f,0.f,0.f,0.f};
            #pragma unroll
            for (int kc = 0; kc < 2; kc++){
                sh8 bq = *(const sh8*)&qs[(mt*16 + lo)*72 + kc*32 + g*8];
                c = __builtin_amdgcn_mfma_f32_16x16x32_bf16(va[kc], bq, c, 0, 0, 0);
            }
            #pragma unroll
            for (int j = 0; j < 4; j++){
                float s = c[j] * INV_N;
                s = fmaxf(s, 0.f);
                Pw[(g*4 + j)*36 + mt*16 + lo] = s*s;
            }
        }

        // ---- pa from P tile ----
        sh8 pa;
        {
            f32x4 p0 = *(const f32x4*)&Pw[lo*36 + g*8];
            f32x4 p1 = *(const f32x4*)&Pw[lo*36 + g*8 + 4];
            union { unsigned u[4]; sh8 v; } pk;
            pk.u[0] = pack2(p0[0], p0[1]); pk.u[1] = pack2(p0[2], p0[3]);
            pk.u[2] = pack2(p1[0], p1[1]); pk.u[3] = pack2(p1[2], p1[3]);
            pa = pk.v;
        }

        // ---- GEMM2: acc += P . k ----
        #pragma unroll
        for (int dt = 0; dt < 3; dt++){
            sh8 bk = *(const sh8*)&ks[(dt*16 + lo)*40 + g*8];
            acc[dt] = __builtin_amdgcn_mfma_f32_16x16x32_bf16(pa, bk, acc[dt], 0, 0, 0);
        }
    }

    // ---- write O: row = row0 + g*4 + j, col = dt*16 + lo ----
    #pragma unroll
    for (int dt = 0; dt < 3; dt++)
        #pragma unroll
        for (int j = 0; j < 4; j++)
            vout[(size_t)(row0 + g*4 + j)*48 + dt*16 + lo] = acc[dt][j];
}

// ---------------- 6. final via bf16 MFMA: out = (xc*gate)@proj + projb + xc ----------------
__global__ __launch_bounds__(256) void k_final(const float* __restrict__ V1,
                                               const float* __restrict__ V2,
                                               const float* __restrict__ gate,
                                               const float* __restrict__ projw,
                                               const float* __restrict__ projb,
                                               float* __restrict__ out){
    __shared__ unsigned short pjbf[96*100];    // [col][k] bf16, stride 100
    int tid  = threadIdx.x;
    int lane = tid & 63;
    int wid  = tid >> 6;
    int lo   = lane & 15;
    int g    = lane >> 4;
    int row0 = blockIdx.x*64 + wid*16;

    // stage proj_w (96x96 fp32, row-major [k][col]) -> pjbf[col][k]
    #pragma unroll
    for (int it = 0; it < 36; it++){
        int idx = tid + it*256;          // 0..9215
        int k = idx / 96, col = idx - k*96;
        pjbf[col*100 + k] = f2bf(projw[idx]);
    }

    // A-fragments: lane holds value[row0+lo][kc*32+g*8 .. +7], value = xc*gate
    sh8 a[3];
    {
        size_t row = row0 + lo;
        const float* gr = gate + row*CC;
        #pragma unroll
        for (int kc = 0; kc < 3; kc++){
            int d0 = kc*32 + g*8;
            const float* xsrc = (d0 < 48) ? (V1 + row*48 + d0) : (V2 + row*48 + d0 - 48);
            f32x4 x0 = *(const f32x4*)xsrc;
            f32x4 x1 = *(const f32x4*)(xsrc + 4);
            f32x4 g0 = *(const f32x4*)(gr + d0);
            f32x4 g1 = *(const f32x4*)(gr + d0 + 4);
            union { unsigned u[4]; sh8 v; } pk;
            pk.u[0] = pack2(x0[0]*g0[0], x0[1]*g0[1]);
            pk.u[1] = pack2(x0[2]*g0[2], x0[3]*g0[3]);
            pk.u[2] = pack2(x1[0]*g1[0], x1[1]*g1[1]);
            pk.u[3] = pack2(x1[2]*g1[2], x1[3]*g1[3]);
            a[kc] = pk.v;
        }
    }
    __syncthreads();

    f32x4 acc[6];
    #pragma unroll
    for (int ct = 0; ct < 6; ct++) acc[ct] = (f32x4){0.f,0.f,0.f,0.f};
    #pragma unroll
    for (int ct = 0; ct < 6; ct++){
        #pragma unroll
        for (int kc = 0; kc < 3; kc++){
            sh8 bw = *(const sh8*)&pjbf[(ct*16 + lo)*100 + kc*32 + g*8];
            acc[ct] = __builtin_amdgcn_mfma_f32_16x16x32_bf16(a[kc], bw, acc[ct], 0, 0, 0);
        }
    }

    // epilogue: out[row][col] = acc + projb[col] + xc[row][col]
    #pragma unroll
    for (int ct = 0; ct < 6; ct++){
        int col = ct*16 + lo;
        float bcol = projb[col];
        const float* xsrc = (ct < 3) ? (V1 + col) : (V2 + col - 48);
        #pragma unroll
        for (int j = 0; j < 4; j++){
            size_t row = row0 + g*4 + j;
            float xc = xsrc[row*48];
            out[row*CC + col] = acc[ct][j] + bcol + xc;
        }
    }
}

extern "C" void kernel_launch(void* const* d_in, const int* in_sizes, int n_in,
                              void* d_out, int out_size, void* d_ws, size_t ws_size,
                              hipStream_t stream){
    const float* x      = (const float*)d_in[0];
    const float* norm_w = (const float*)d_in[3];
    const float* norm_b = (const float*)d_in[4];
    const float* Wh     = (const float*)d_in[5];
    const float* bh     = (const float*)d_in[6];
    const float* Wqk    = (const float*)d_in[7];
    const float* bqk    = (const float*)d_in[8];
    const float* g1     = (const float*)d_in[9];
    const float* be1    = (const float*)d_in[10];
    const float* g2     = (const float*)d_in[11];
    const float* be2    = (const float*)d_in[12];
    const float* sr1_w  = (const float*)d_in[13];
    const float* sr1_b  = (const float*)d_in[14];
    const float* sr2_w  = (const float*)d_in[15];
    const float* sr2_b  = (const float*)d_in[16];
    const float* n1_w   = (const float*)d_in[17];
    const float* n1_b   = (const float*)d_in[18];
    const float* n2_w   = (const float*)d_in[19];
    const float* n2_b   = (const float*)d_in[20];
    const float* proj_w = (const float*)d_in[21];
    const float* proj_b = (const float*)d_in[22];
    float* out = (float*)d_out;

    float* ws = (float*)d_ws;
    size_t off = 0;
    float* nx   = ws + off; off += (size_t)NB*NTOK*CC;
    float* vbuf = ws + off; off += (size_t)NB*NTOK*CC;
    float* gate = ws + off; off += (size_t)NB*NTOK*CC;
    unsigned short* qp1 = (unsigned short*)(ws + off); off += (size_t)NB*256*64/2;
    unsigned short* kt1 = (unsigned short*)(ws + off); off += (size_t)NB*48*256/2;
    unsigned short* qp2 = (unsigned short*)(ws + off); off += (size_t)NB*1024*64/2;
    unsigned short* kt2 = (unsigned short*)(ws + off); off += (size_t)NB*48*1024/2;
    float* part1= ws + off; off += (size_t)32*NB*256*96;
    float* part2= ws + off; off += (size_t)8*NB*1024*96;
    float* V1   = ws + off; off += (size_t)NB*NTOK*48;
    float* V2   = ws + off; off += (size_t)NB*NTOK*48;
    if (ws_size < off*sizeof(float)) return;

    k_ln   <<<16384, 256, 0, stream>>>(x, norm_w, norm_b, nx);
    k_hgemm<<<1024, 256, 0, stream>>>(nx, Wh, bh, vbuf, gate);
    k_conv <<<512, 256, 0, stream>>>(nx, sr1_w, part1, 8, 4, 3, 6144);
    k_conv <<<512, 256, 0, stream>>>(nx, sr2_w, part2, 10, 5, 2, 1536);
    k_reduce<<<1024, 64, 0, stream>>>(part1, 32, 1024, 256, sr1_b, n1_w, n1_b, Wqk, bqk, g1, be1, qp1, kt1);
    k_reduce<<<4096, 64, 0, stream>>>(part2, 8, 4096, 1024, sr2_b, n2_w, n2_b, Wqk, bqk, g2, be2, qp2, kt2);
    k_attn <<<2048, 256, 0, stream>>>(vbuf, qp1, kt1, qp2, kt2, V1, V2);
    k_final<<<1024, 256, 0, stream>>>(V1, V2, gate, proj_w, proj_b, out);
}

// Round 10
// 153.615 us; speedup vs baseline: 2.0556x; 1.3728x over previous
//
#include <hip/hip_runtime.h>
#include <math.h>

#define NB   4
#define IH   128
#define IW   128
#define NTOK 16384        // IH*IW
#define CC   96
#define HID  192
#define QKD  48
#define EPSF 1e-5f
#define INV_N (1.0f/16384.0f)

typedef __attribute__((ext_vector_type(8))) short sh8;    // 8 bf16 (4 VGPRs)
typedef __attribute__((ext_vector_type(4))) short ush4;   // 4 bf16 (2 VGPRs)
typedef __attribute__((ext_vector_type(4))) float f32x4;  // 4 fp32

__device__ __forceinline__ float wave_sum64(float v){
    #pragma unroll
    for (int off = 32; off > 0; off >>= 1) v += __shfl_xor(v, off, 64);
    return v;
}
__device__ __forceinline__ float siluf(float x){ return x / (1.0f + __expf(-x)); }
__device__ __forceinline__ float geluf(float x){ return 0.5f*x*(1.0f + erff(x*0.7071067811865475f)); }

__device__ __forceinline__ unsigned short f2bf(float f){   // RNE float->bf16 bits
    union { float f; unsigned u; } x; x.f = f;
    unsigned u = x.u + 0x7FFFu + ((x.u >> 16) & 1u);
    return (unsigned short)(u >> 16);
}
__device__ __forceinline__ unsigned pack2(float a, float b){
    return (unsigned)f2bf(a) | ((unsigned)f2bf(b) << 16);
}

// ---------------- 0. one-off: conv weights fp32 -> bf16 ----------------
__global__ __launch_bounds__(256) void k_cvt(const float* __restrict__ s1, unsigned short* __restrict__ d1, int n1,
                                             const float* __restrict__ s2, unsigned short* __restrict__ d2, int n2){
    int i4 = (blockIdx.x*256 + threadIdx.x)*4;
    if (i4 < n1){
        float4 v = *(const float4*)(s1 + i4);
        ush4 o = {(short)f2bf(v.x), (short)f2bf(v.y), (short)f2bf(v.z), (short)f2bf(v.w)};
        *(ush4*)(d1 + i4) = o;
    } else {
        int j = i4 - n1;
        if (j < n2){
            float4 v = *(const float4*)(s2 + j);
            ush4 o = {(short)f2bf(v.x), (short)f2bf(v.y), (short)f2bf(v.z), (short)f2bf(v.w)};
            *(ush4*)(d2 + j) = o;
        }
    }
}

// ---------------- 1. LayerNorm -> bf16, token-major (nxbf) + image-major (nxim) ----------------
__global__ __launch_bounds__(256) void k_ln(const float* __restrict__ x,
                                            const float* __restrict__ w,
                                            const float* __restrict__ bb,
                                            unsigned short* __restrict__ nxbf,
                                            unsigned short* __restrict__ nxim){
    __shared__ unsigned short tile[4][96];
    int r = threadIdx.x >> 6;
    int row = blockIdx.x*4 + r;
    int l = threadIdx.x & 63;
    const float* xr = x + (size_t)row*CC;
    float a = xr[l];
    float b = (l < 32) ? xr[64+l] : 0.0f;
    float s = wave_sum64(a + b);
    float m = s * (1.0f/96.0f);
    float d1 = a - m;
    float d2 = b - m;
    float sq = d1*d1 + ((l < 32) ? d2*d2 : 0.0f);
    float var = wave_sum64(sq) * (1.0f/96.0f);
    float rstd = rsqrtf(var + EPSF);
    unsigned short b1 = f2bf(d1*rstd*w[l] + bb[l]);
    nxbf[(size_t)row*CC + l] = b1;
    tile[r][l] = b1;
    if (l < 32){
        unsigned short b2 = f2bf(d2*rstd*w[64+l] + bb[64+l]);
        nxbf[(size_t)row*CC + 64 + l] = b2;
        tile[r][64+l] = b2;
    }
    __syncthreads();
    int t = threadIdx.x;
    if (t < 96){
        int row0 = blockIdx.x*4;
        int bb2 = row0 >> 14, hw = row0 & 16383;
        ush4 v = {(short)tile[0][t], (short)tile[1][t], (short)tile[2][t], (short)tile[3][t]};
        *(ush4*)(nxim + (((size_t)(bb2*96 + t)) << 14) + hw) = v;
    }
}

// ---------------- 2. h = silu(nxbf @ Wh + bh) via bf16 MFMA; split v/gate ----------------
__global__ __launch_bounds__(256) void k_hgemm(const unsigned short* __restrict__ nxbf,
                                               const float* __restrict__ Wh,
                                               const float* __restrict__ bh,
                                               float* __restrict__ vbuf,
                                               float* __restrict__ gate){
    __shared__ unsigned short whbf[192*100];   // [col][k] bf16, stride 100
    int tid  = threadIdx.x;
    int lane = tid & 63;
    int wid  = tid >> 6;
    int lo   = lane & 15;
    int g    = lane >> 4;
    int row0 = blockIdx.x*64 + wid*16;

    #pragma unroll
    for (int it = 0; it < 72; it++){
        int idx = tid + it*256;          // 0..18431
        int k = idx / 192, col = idx - k*192;
        whbf[col*100 + k] = f2bf(Wh[idx]);
    }

    // A-fragments: direct bf16 16B loads
    sh8 a[3];
    {
        const unsigned short* ar = nxbf + (size_t)(row0 + lo)*CC;
        #pragma unroll
        for (int kc = 0; kc < 3; kc++)
            a[kc] = *(const sh8*)(ar + kc*32 + g*8);
    }
    __syncthreads();

    f32x4 acc[12];
    #pragma unroll
    for (int ct = 0; ct < 12; ct++) acc[ct] = (f32x4){0.f,0.f,0.f,0.f};
    #pragma unroll
    for (int ct = 0; ct < 12; ct++){
        #pragma unroll
        for (int kc = 0; kc < 3; kc++){
            sh8 bw = *(const sh8*)&whbf[(ct*16 + lo)*100 + kc*32 + g*8];
            acc[ct] = __builtin_amdgcn_mfma_f32_16x16x32_bf16(a[kc], bw, acc[ct], 0, 0, 0);
        }
    }

    #pragma unroll
    for (int ct = 0; ct < 12; ct++){
        int col = ct*16 + lo;
        float bcol = bh[col];
        #pragma unroll
        for (int j = 0; j < 4; j++){
            size_t row = row0 + g*4 + j;
            float hv = siluf(acc[ct][j] + bcol);
            if (col < 96) vbuf[row*CC + col] = hv;
            else          gate[row*CC + col - 96] = hv;
        }
    }
}

// ---------------- 3. conv via bf16 MFMA (patch GEMM, K-split, prefetched memcpy staging) ----------------
// Block = 64 positions x 96 out, Ksplit = 192 = 3 chunks of 64. nxim: [b][c][h][w] bf16.
__global__ __launch_bounds__(256) void k_conv(const unsigned short* __restrict__ nxim,
                                              const unsigned short* __restrict__ wbf,
                                              float* __restrict__ part,
                                              int posLog, int pdimLog, int pszLog,
                                              int kTotal, int rowblocks){
    __shared__ unsigned short pt[64*72];   // [pos][k] stride 72
    __shared__ unsigned short wt[96*72];   // [o][k]  stride 72
    int bx = blockIdx.x;
    int rb = bx % rowblocks;
    int split = bx / rowblocks;
    int tid = threadIdx.x;
    int lane = tid & 63, wid = tid >> 6, lo = lane & 15, g = lane >> 4;
    int psz = 1 << pszLog, pdim = 1 << pdimLog;
    int ksLog = 2*pszLog;
    int kb0 = split * 192;
    int cinc = (64 >> ksLog) << 14;       // per-chunk image-address increment

    // patch segs (4 per thread, 8B each): sid = tid + i*256 -> p = tid>>4 + 16i, j = tid&15
    int j   = tid & 15;
    int coff = (j*4) >> ksLog;            // 0 for conv1; j>>2 for conv2
    int s   = (j*4) & (psz*psz - 1);
    int sy  = s >> pszLog, sx = s & (psz-1);
    int pAddr[4], pOff[4];
    #pragma unroll
    for (int i = 0; i < 4; i++){
        int p = (tid >> 4) + 16*i;
        int R = rb*64 + p;
        int b = R >> posLog, pp = R & ((1 << posLog) - 1);
        int pi = pp >> pdimLog, pj = pp & (pdim-1);
        pAddr[i] = (((b*96 + coff) + (kb0 >> ksLog)) << 14) + (pi*psz + sy)*IW + pj*psz + sx;
        pOff[i]  = p*72 + j*4;
    }
    // weight segs (3 per thread, 16B each): o = tid>>3 + 32i, jj = tid&7
    int jj = tid & 7;
    int wAddr[3], wOff[3];
    #pragma unroll
    for (int i = 0; i < 3; i++){
        int o = (tid >> 3) + 32*i;
        wAddr[i] = o*kTotal + kb0 + jj*8;
        wOff[i]  = o*72 + jj*8;
    }

    f32x4 acc[6];
    #pragma unroll
    for (int ct = 0; ct < 6; ct++) acc[ct] = (f32x4){0.f,0.f,0.f,0.f};

    // prologue: prefetch chunk 0
    ush4 pr[4]; sh8 wr[3];
    #pragma unroll
    for (int i = 0; i < 4; i++) pr[i] = *(const ush4*)(nxim + pAddr[i]);
    #pragma unroll
    for (int i = 0; i < 3; i++) wr[i] = *(const sh8*)(wbf + wAddr[i]);

    for (int ch = 0; ch < 3; ch++){
        __syncthreads();                  // WAR on pt/wt
        #pragma unroll
        for (int i = 0; i < 4; i++) *(ush4*)&pt[pOff[i]] = pr[i];
        #pragma unroll
        for (int i = 0; i < 3; i++) *(sh8*)&wt[wOff[i]] = wr[i];
        if (ch < 2){                      // issue next chunk's loads under compute
            #pragma unroll
            for (int i = 0; i < 4; i++){ pAddr[i] += cinc; pr[i] = *(const ush4*)(nxim + pAddr[i]); }
            #pragma unroll
            for (int i = 0; i < 3; i++){ wAddr[i] += 64;  wr[i] = *(const sh8*)(wbf + wAddr[i]); }
        }
        __syncthreads();

        sh8 a0 = *(const sh8*)&pt[(wid*16 + lo)*72 + g*8];
        sh8 a1 = *(const sh8*)&pt[(wid*16 + lo)*72 + 32 + g*8];
        #pragma unroll
        for (int ct = 0; ct < 6; ct++){
            sh8 b0 = *(const sh8*)&wt[(ct*16 + lo)*72 + g*8];
            sh8 b1 = *(const sh8*)&wt[(ct*16 + lo)*72 + 32 + g*8];
            acc[ct] = __builtin_amdgcn_mfma_f32_16x16x32_bf16(a0, b0, acc[ct], 0, 0, 0);
            acc[ct] = __builtin_amdgcn_mfma_f32_16x16x32_bf16(a1, b1, acc[ct], 0, 0, 0);
        }
    }

    int rowsTotal = NB << posLog;
    #pragma unroll
    for (int ct = 0; ct < 6; ct++){
        int o = ct*16 + lo;
        #pragma unroll
        for (int jx = 0; jx < 4; jx++){
            int R = rb*64 + wid*16 + g*4 + jx;
            part[((size_t)split*rowsTotal + R)*96 + o] = acc[ct][jx];
        }
    }
}

// ---------------- 4. reduce K-splits + bias + LN + gelu + Z/q/k -> bf16 qp/ktp ----------------
__global__ __launch_bounds__(64) void k_reduce(const float* __restrict__ part,
                                               int nsplit, int rows, int Mper,
                                               const float* __restrict__ cbias,
                                               const float* __restrict__ lw,
                                               const float* __restrict__ lb,
                                               const float* __restrict__ wqk,
                                               const float* __restrict__ bqk,
                                               const float* __restrict__ g,
                                               const float* __restrict__ be,
                                               unsigned short* __restrict__ qp,
                                               unsigned short* __restrict__ ktp){
    __shared__ float xsh[96];
    int row = blockIdx.x;
    int l = threadIdx.x;
    float y1 = 0.0f, y2 = 0.0f;
    for (int s = 0; s < nsplit; s++){
        const float* pr = part + ((size_t)s*rows + row)*96;
        y1 += pr[l];
        if (l < 32) y2 += pr[64+l];
    }
    y1 += cbias[l];
    if (l < 32) y2 += cbias[64+l];
    float s = wave_sum64(y1 + ((l < 32) ? y2 : 0.0f));
    float m = s * (1.0f/96.0f);
    float d1 = y1 - m, d2 = y2 - m;
    float var = wave_sum64(d1*d1 + ((l < 32) ? d2*d2 : 0.0f)) * (1.0f/96.0f);
    float rstd = rsqrtf(var + EPSF);
    xsh[l] = geluf(d1*rstd*lw[l] + lb[l]);
    if (l < 32) xsh[64+l] = geluf(d2*rstd*lw[64+l] + lb[64+l]);
    __syncthreads();
    if (l < 48){
        float z = bqk[l];
        #pragma unroll 4
        for (int c = 0; c < 96; c++) z += xsh[c]*wqk[c*48 + l];
        z = siluf(z);
        float qv = z*g[l]    + be[l];
        float kv = z*g[48+l] + be[48+l];
        int b = row / Mper, p = row - b*Mper;
        qp[(size_t)row*64 + l] = f2bf(qv);
        ktp[((size_t)b*48 + l)*Mper + p] = f2bf(kv);
    } else {
        qp[(size_t)row*64 + l] = 0;      // zero the d-pad
    }
}

// ---------------- 5. attention via bf16 MFMA, LDS-staged bf16 with async prefetch ----------------
__global__ __launch_bounds__(256) void k_attn(const float* __restrict__ vbuf,
                                              const unsigned short* __restrict__ qp1,
                                              const unsigned short* __restrict__ ktp1,
                                              const unsigned short* __restrict__ qp2,
                                              const unsigned short* __restrict__ ktp2,
                                              float* __restrict__ V1,
                                              float* __restrict__ V2){
    __shared__ unsigned short qs[32*72];    // q[m][d] chunk, stride 72
    __shared__ unsigned short ks[48*40];    // kT[d][m] chunk, stride 40
    __shared__ float Pl[4][16*36];          // per-wave P tile [16n][32m]

    int bx   = blockIdx.x;
    int kind = bx >> 10;
    int blk  = bx & 1023;
    int tid  = threadIdx.x;
    int wid  = tid >> 6;
    int lane = tid & 63;
    int lo   = lane & 15;
    int g    = lane >> 4;
    int row0 = blk*64 + wid*16;
    int b    = row0 >> 14;

    int   M    = kind ? 1024 : 256;
    const unsigned short* qp = (kind ? qp2 : qp1) + (size_t)b*M*64;
    const unsigned short* kt = (kind ? ktp2 : ktp1) + (size_t)b*48*M;
    int   voff = kind ? 48 : 0;
    float* vout = kind ? V2 : V1;

    sh8 va[2];
    {
        const float* vrow = vbuf + (size_t)(row0 + lo)*CC + voff;
        union { unsigned u[4]; sh8 v; } pk;
        f32x4 a0 = *(const f32x4*)(vrow + g*8);
        f32x4 a1 = *(const f32x4*)(vrow + g*8 + 4);
        pk.u[0] = pack2(a0[0], a0[1]); pk.u[1] = pack2(a0[2], a0[3]);
        pk.u[2] = pack2(a1[0], a1[1]); pk.u[3] = pack2(a1[2], a1[3]);
        va[0] = pk.v;
        if (g < 2){
            f32x4 b0 = *(const f32x4*)(vrow + 32 + g*8);
            f32x4 b1 = *(const f32x4*)(vrow + 32 + g*8 + 4);
            pk.u[0] = pack2(b0[0], b0[1]); pk.u[1] = pack2(b0[2], b0[3]);
            pk.u[2] = pack2(b1[0], b1[1]); pk.u[3] = pack2(b1[2], b1[3]);
        } else {
            pk.u[0] = 0u; pk.u[1] = 0u; pk.u[2] = 0u; pk.u[3] = 0u;
        }
        va[1] = pk.v;
    }

    int qm = tid >> 3, qj = tid & 7;
    int kd = tid >> 2, kj = tid & 3;
    bool kact = tid < 192;

    f32x4 acc[3];
    acc[0] = (f32x4){0.f,0.f,0.f,0.f};
    acc[1] = (f32x4){0.f,0.f,0.f,0.f};
    acc[2] = (f32x4){0.f,0.f,0.f,0.f};
    float* Pw = Pl[wid];
    int nchunk = M >> 5;

    sh8 qreg = *(const sh8*)(qp + (size_t)qm*64 + qj*8);
    sh8 kreg;
    if (kact) kreg = *(const sh8*)(kt + (size_t)kd*M + kj*8);

    for (int ch = 0; ch < nchunk; ch++){
        int mb = ch*32;
        __syncthreads();
        *(sh8*)&qs[qm*72 + qj*8] = qreg;
        if (kact) *(sh8*)&ks[kd*40 + kj*8] = kreg;
        if (ch + 1 < nchunk){
            int mb2 = mb + 32;
            qreg = *(const sh8*)(qp + (size_t)(mb2 + qm)*64 + qj*8);
            if (kact) kreg = *(const sh8*)(kt + (size_t)kd*M + mb2 + kj*8);
        }
        __syncthreads();

        #pragma unroll
        for (int mt = 0; mt < 2; mt++){
            f32x4 c = (f32x4){0.f,0.f,0.f,0.f};
            #pragma unroll
            for (int kc = 0; kc < 2; kc++){
                sh8 bq = *(const sh8*)&qs[(mt*16 + lo)*72 + kc*32 + g*8];
                c = __builtin_amdgcn_mfma_f32_16x16x32_bf16(va[kc], bq, c, 0, 0, 0);
            }
            #pragma unroll
            for (int j = 0; j < 4; j++){
                float s = c[j] * INV_N;
                s = fmaxf(s, 0.f);
                Pw[(g*4 + j)*36 + mt*16 + lo] = s*s;
            }
        }

        sh8 pa;
        {
            f32x4 p0 = *(const f32x4*)&Pw[lo*36 + g*8];
            f32x4 p1 = *(const f32x4*)&Pw[lo*36 + g*8 + 4];
            union { unsigned u[4]; sh8 v; } pk;
            pk.u[0] = pack2(p0[0], p0[1]); pk.u[1] = pack2(p0[2], p0[3]);
            pk.u[2] = pack2(p1[0], p1[1]); pk.u[3] = pack2(p1[2], p1[3]);
            pa = pk.v;
        }

        #pragma unroll
        for (int dt = 0; dt < 3; dt++){
            sh8 bk = *(const sh8*)&ks[(dt*16 + lo)*40 + g*8];
            acc[dt] = __builtin_amdgcn_mfma_f32_16x16x32_bf16(pa, bk, acc[dt], 0, 0, 0);
        }
    }

    #pragma unroll
    for (int dt = 0; dt < 3; dt++)
        #pragma unroll
        for (int j = 0; j < 4; j++)
            vout[(size_t)(row0 + g*4 + j)*48 + dt*16 + lo] = acc[dt][j];
}

// ---------------- 6. final via bf16 MFMA: out = (xc*gate)@proj + projb + xc ----------------
__global__ __launch_bounds__(256) void k_final(const float* __restrict__ V1,
                                               const float* __restrict__ V2,
                                               const float* __restrict__ gate,
                                               const float* __restrict__ projw,
                                               const float* __restrict__ projb,
                                               float* __restrict__ out){
    __shared__ unsigned short pjbf[96*100];    // [col][k] bf16, stride 100
    int tid  = threadIdx.x;
    int lane = tid & 63;
    int wid  = tid >> 6;
    int lo   = lane & 15;
    int g    = lane >> 4;
    int row0 = blockIdx.x*64 + wid*16;

    #pragma unroll
    for (int it = 0; it < 36; it++){
        int idx = tid + it*256;          // 0..9215
        int k = idx / 96, col = idx - k*96;
        pjbf[col*100 + k] = f2bf(projw[idx]);
    }

    sh8 a[3];
    {
        size_t row = row0 + lo;
        const float* gr = gate + row*CC;
        #pragma unroll
        for (int kc = 0; kc < 3; kc++){
            int d0 = kc*32 + g*8;
            const float* xsrc = (d0 < 48) ? (V1 + row*48 + d0) : (V2 + row*48 + d0 - 48);
            f32x4 x0 = *(const f32x4*)xsrc;
            f32x4 x1 = *(const f32x4*)(xsrc + 4);
            f32x4 g0 = *(const f32x4*)(gr + d0);
            f32x4 g1 = *(const f32x4*)(gr + d0 + 4);
            union { unsigned u[4]; sh8 v; } pk;
            pk.u[0] = pack2(x0[0]*g0[0], x0[1]*g0[1]);
            pk.u[1] = pack2(x0[2]*g0[2], x0[3]*g0[3]);
            pk.u[2] = pack2(x1[0]*g1[0], x1[1]*g1[1]);
            pk.u[3] = pack2(x1[2]*g1[2], x1[3]*g1[3]);
            a[kc] = pk.v;
        }
    }
    __syncthreads();

    f32x4 acc[6];
    #pragma unroll
    for (int ct = 0; ct < 6; ct++) acc[ct] = (f32x4){0.f,0.f,0.f,0.f};
    #pragma unroll
    for (int ct = 0; ct < 6; ct++){
        #pragma unroll
        for (int kc = 0; kc < 3; kc++){
            sh8 bw = *(const sh8*)&pjbf[(ct*16 + lo)*100 + kc*32 + g*8];
            acc[ct] = __builtin_amdgcn_mfma_f32_16x16x32_bf16(a[kc], bw, acc[ct], 0, 0, 0);
        }
    }

    #pragma unroll
    for (int ct = 0; ct < 6; ct++){
        int col = ct*16 + lo;
        float bcol = projb[col];
        const float* xsrc = (ct < 3) ? (V1 + col) : (V2 + col - 48);
        #pragma unroll
        for (int j = 0; j < 4; j++){
            size_t row = row0 + g*4 + j;
            float xc = xsrc[row*48];
            out[row*CC + col] = acc[ct][j] + bcol + xc;
        }
    }
}

extern "C" void kernel_launch(void* const* d_in, const int* in_sizes, int n_in,
                              void* d_out, int out_size, void* d_ws, size_t ws_size,
                              hipStream_t stream){
    const float* x      = (const float*)d_in[0];
    const float* norm_w = (const float*)d_in[3];
    const float* norm_b = (const float*)d_in[4];
    const float* Wh     = (const float*)d_in[5];
    const float* bh     = (const float*)d_in[6];
    const float* Wqk    = (const float*)d_in[7];
    const float* bqk    = (const float*)d_in[8];
    const float* g1     = (const float*)d_in[9];
    const float* be1    = (const float*)d_in[10];
    const float* g2     = (const float*)d_in[11];
    const float* be2    = (const float*)d_in[12];
    const float* sr1_w  = (const float*)d_in[13];
    const float* sr1_b  = (const float*)d_in[14];
    const float* sr2_w  = (const float*)d_in[15];
    const float* sr2_b  = (const float*)d_in[16];
    const float* n1_w   = (const float*)d_in[17];
    const float* n1_b   = (const float*)d_in[18];
    const float* n2_w   = (const float*)d_in[19];
    const float* n2_b   = (const float*)d_in[20];
    const float* proj_w = (const float*)d_in[21];
    const float* proj_b = (const float*)d_in[22];
    float* out = (float*)d_out;

    float* ws = (float*)d_ws;
    size_t off = 0;
    unsigned short* nxbf = (unsigned short*)(ws + off); off += (size_t)NB*NTOK*CC/2;
    unsigned short* nxim = (unsigned short*)(ws + off); off += (size_t)NB*NTOK*CC/2;
    unsigned short* w1bf = (unsigned short*)(ws + off); off += (size_t)96*6144/2;
    unsigned short* w2bf = (unsigned short*)(ws + off); off += (size_t)96*1536/2;
    float* vbuf = ws + off; off += (size_t)NB*NTOK*CC;
    float* gate = ws + off; off += (size_t)NB*NTOK*CC;
    unsigned short* qp1 = (unsigned short*)(ws + off); off += (size_t)NB*256*64/2;
    unsigned short* kt1 = (unsigned short*)(ws + off); off += (size_t)NB*48*256/2;
    unsigned short* qp2 = (unsigned short*)(ws + off); off += (size_t)NB*1024*64/2;
    unsigned short* kt2 = (unsigned short*)(ws + off); off += (size_t)NB*48*1024/2;
    float* part1= ws + off; off += (size_t)32*NB*256*96;
    float* part2= ws + off; off += (size_t)8*NB*1024*96;
    float* V1   = ws + off; off += (size_t)NB*NTOK*48;
    float* V2   = ws + off; off += (size_t)NB*NTOK*48;
    if (ws_size < off*sizeof(float)) return;

    k_cvt  <<<720, 256, 0, stream>>>(sr1_w, w1bf, 96*6144, sr2_w, w2bf, 96*1536);
    k_ln   <<<16384, 256, 0, stream>>>(x, norm_w, norm_b, nxbf, nxim);
    k_hgemm<<<1024, 256, 0, stream>>>(nxbf, Wh, bh, vbuf, gate);
    k_conv <<<512, 256, 0, stream>>>(nxim, w1bf, part1, 8, 4, 3, 6144, 16);
    k_conv <<<512, 256, 0, stream>>>(nxim, w2bf, part2, 10, 5, 2, 1536, 64);
    k_reduce<<<1024, 64, 0, stream>>>(part1, 32, 1024, 256, sr1_b, n1_w, n1_b, Wqk, bqk, g1, be1, qp1, kt1);
    k_reduce<<<4096, 64, 0, stream>>>(part2, 8, 4096, 1024, sr2_b, n2_w, n2_b, Wqk, bqk, g2, be2, qp2, kt2);
    k_attn <<<2048, 256, 0, stream>>>(vbuf, qp1, kt1, qp2, kt2, V1, V2);
    k_final<<<1024, 256, 0, stream>>>(V1, V2, gate, proj_w, proj_b, out);
}

// Round 11
// 144.497 us; speedup vs baseline: 2.1853x; 1.0631x over previous
//
#include <hip/hip_runtime.h>
#include <math.h>

#define NB   4
#define IH   128
#define IW   128
#define NTOK 16384        // IH*IW
#define CC   96
#define HID  192
#define QKD  48
#define EPSF 1e-5f
#define INV_N (1.0f/16384.0f)

typedef __attribute__((ext_vector_type(8))) short sh8;    // 8 bf16 (4 VGPRs)
typedef __attribute__((ext_vector_type(4))) short ush4;   // 4 bf16 (2 VGPRs)
typedef __attribute__((ext_vector_type(4))) float f32x4;  // 4 fp32

__device__ __forceinline__ float wave_sum64(float v){
    #pragma unroll
    for (int off = 32; off > 0; off >>= 1) v += __shfl_xor(v, off, 64);
    return v;
}
__device__ __forceinline__ float siluf(float x){ return x / (1.0f + __expf(-x)); }
__device__ __forceinline__ float geluf(float x){ return 0.5f*x*(1.0f + erff(x*0.7071067811865475f)); }

__device__ __forceinline__ unsigned short f2bf(float f){   // RNE float->bf16 bits
    union { float f; unsigned u; } x; x.f = f;
    unsigned u = x.u + 0x7FFFu + ((x.u >> 16) & 1u);
    return (unsigned short)(u >> 16);
}
__device__ __forceinline__ unsigned pack2(float a, float b){
    return (unsigned)f2bf(a) | ((unsigned)f2bf(b) << 16);
}
// gfx950 cross-lane half-swaps (both operands modified):
// swap32: x'[32:63]=y[0:31], y'[0:31]=x[32:63]  -> x'={x.lo,y.lo}, y'={x.hi,y.hi}
// swap16: x'[16:31]=y[0:15], y'[0:15]=x[16:31] (and same for upper half)
__device__ __forceinline__ void swap32(unsigned &x, unsigned &y){
    asm volatile("v_permlane32_swap_b32 %0, %1" : "+v"(x), "+v"(y));
}
__device__ __forceinline__ void swap16(unsigned &x, unsigned &y){
    asm volatile("v_permlane16_swap_b32 %0, %1" : "+v"(x), "+v"(y));
}

// ---------------- 0. one-off: conv weights fp32 -> bf16 ----------------
__global__ __launch_bounds__(256) void k_cvt(const float* __restrict__ s1, unsigned short* __restrict__ d1, int n1,
                                             const float* __restrict__ s2, unsigned short* __restrict__ d2, int n2){
    int i4 = (blockIdx.x*256 + threadIdx.x)*4;
    if (i4 < n1){
        float4 v = *(const float4*)(s1 + i4);
        ush4 o = {(short)f2bf(v.x), (short)f2bf(v.y), (short)f2bf(v.z), (short)f2bf(v.w)};
        *(ush4*)(d1 + i4) = o;
    } else {
        int j = i4 - n1;
        if (j < n2){
            float4 v = *(const float4*)(s2 + j);
            ush4 o = {(short)f2bf(v.x), (short)f2bf(v.y), (short)f2bf(v.z), (short)f2bf(v.w)};
            *(ush4*)(d2 + j) = o;
        }
    }
}

// ---------------- 1. LayerNorm -> bf16, token-major (nxbf) + image-major (nxim) ----------------
__global__ __launch_bounds__(256) void k_ln(const float* __restrict__ x,
                                            const float* __restrict__ w,
                                            const float* __restrict__ bb,
                                            unsigned short* __restrict__ nxbf,
                                            unsigned short* __restrict__ nxim){
    __shared__ unsigned short tile[4][96];
    int r = threadIdx.x >> 6;
    int row = blockIdx.x*4 + r;
    int l = threadIdx.x & 63;
    const float* xr = x + (size_t)row*CC;
    float a = xr[l];
    float b = (l < 32) ? xr[64+l] : 0.0f;
    float s = wave_sum64(a + b);
    float m = s * (1.0f/96.0f);
    float d1 = a - m;
    float d2 = b - m;
    float sq = d1*d1 + ((l < 32) ? d2*d2 : 0.0f);
    float var = wave_sum64(sq) * (1.0f/96.0f);
    float rstd = rsqrtf(var + EPSF);
    unsigned short b1 = f2bf(d1*rstd*w[l] + bb[l]);
    nxbf[(size_t)row*CC + l] = b1;
    tile[r][l] = b1;
    if (l < 32){
        unsigned short b2 = f2bf(d2*rstd*w[64+l] + bb[64+l]);
        nxbf[(size_t)row*CC + 64 + l] = b2;
        tile[r][64+l] = b2;
    }
    __syncthreads();
    int t = threadIdx.x;
    if (t < 96){
        int row0 = blockIdx.x*4;
        int bb2 = row0 >> 14, hw = row0 & 16383;
        ush4 v = {(short)tile[0][t], (short)tile[1][t], (short)tile[2][t], (short)tile[3][t]};
        *(ush4*)(nxim + (((size_t)(bb2*96 + t)) << 14) + hw) = v;
    }
}

// ---------------- 2. h = silu(nxbf @ Wh + bh) via bf16 MFMA; split v/gate ----------------
__global__ __launch_bounds__(256) void k_hgemm(const unsigned short* __restrict__ nxbf,
                                               const float* __restrict__ Wh,
                                               const float* __restrict__ bh,
                                               float* __restrict__ vbuf,
                                               float* __restrict__ gate){
    __shared__ unsigned short whbf[192*100];   // [col][k] bf16, stride 100
    int tid  = threadIdx.x;
    int lane = tid & 63;
    int wid  = tid >> 6;
    int lo   = lane & 15;
    int g    = lane >> 4;
    int row0 = blockIdx.x*64 + wid*16;

    #pragma unroll
    for (int it = 0; it < 72; it++){
        int idx = tid + it*256;          // 0..18431
        int k = idx / 192, col = idx - k*192;
        whbf[col*100 + k] = f2bf(Wh[idx]);
    }

    // A-fragments: direct bf16 16B loads
    sh8 a[3];
    {
        const unsigned short* ar = nxbf + (size_t)(row0 + lo)*CC;
        #pragma unroll
        for (int kc = 0; kc < 3; kc++)
            a[kc] = *(const sh8*)(ar + kc*32 + g*8);
    }
    __syncthreads();

    f32x4 acc[12];
    #pragma unroll
    for (int ct = 0; ct < 12; ct++) acc[ct] = (f32x4){0.f,0.f,0.f,0.f};
    #pragma unroll
    for (int ct = 0; ct < 12; ct++){
        #pragma unroll
        for (int kc = 0; kc < 3; kc++){
            sh8 bw = *(const sh8*)&whbf[(ct*16 + lo)*100 + kc*32 + g*8];
            acc[ct] = __builtin_amdgcn_mfma_f32_16x16x32_bf16(a[kc], bw, acc[ct], 0, 0, 0);
        }
    }

    #pragma unroll
    for (int ct = 0; ct < 12; ct++){
        int col = ct*16 + lo;
        float bcol = bh[col];
        #pragma unroll
        for (int j = 0; j < 4; j++){
            size_t row = row0 + g*4 + j;
            float hv = siluf(acc[ct][j] + bcol);
            if (col < 96) vbuf[row*CC + col] = hv;
            else          gate[row*CC + col - 96] = hv;
        }
    }
}

// ---------------- 3. conv via bf16 MFMA (patch GEMM, K-split, prefetched memcpy staging) ----------------
__global__ __launch_bounds__(256) void k_conv(const unsigned short* __restrict__ nxim,
                                              const unsigned short* __restrict__ wbf,
                                              float* __restrict__ part,
                                              int posLog, int pdimLog, int pszLog,
                                              int kTotal, int rowblocks){
    __shared__ unsigned short pt[64*72];   // [pos][k] stride 72
    __shared__ unsigned short wt[96*72];   // [o][k]  stride 72
    int bx = blockIdx.x;
    int rb = bx % rowblocks;
    int split = bx / rowblocks;
    int tid = threadIdx.x;
    int lane = tid & 63, wid = tid >> 6, lo = lane & 15, g = lane >> 4;
    int psz = 1 << pszLog, pdim = 1 << pdimLog;
    int ksLog = 2*pszLog;
    int kb0 = split * 192;
    int cinc = (64 >> ksLog) << 14;       // per-chunk image-address increment

    int j   = tid & 15;
    int coff = (j*4) >> ksLog;
    int s   = (j*4) & (psz*psz - 1);
    int sy  = s >> pszLog, sx = s & (psz-1);
    int pAddr[4], pOff[4];
    #pragma unroll
    for (int i = 0; i < 4; i++){
        int p = (tid >> 4) + 16*i;
        int R = rb*64 + p;
        int b = R >> posLog, pp = R & ((1 << posLog) - 1);
        int pi = pp >> pdimLog, pj = pp & (pdim-1);
        pAddr[i] = (((b*96 + coff) + (kb0 >> ksLog)) << 14) + (pi*psz + sy)*IW + pj*psz + sx;
        pOff[i]  = p*72 + j*4;
    }
    int jj = tid & 7;
    int wAddr[3], wOff[3];
    #pragma unroll
    for (int i = 0; i < 3; i++){
        int o = (tid >> 3) + 32*i;
        wAddr[i] = o*kTotal + kb0 + jj*8;
        wOff[i]  = o*72 + jj*8;
    }

    f32x4 acc[6];
    #pragma unroll
    for (int ct = 0; ct < 6; ct++) acc[ct] = (f32x4){0.f,0.f,0.f,0.f};

    ush4 pr[4]; sh8 wr[3];
    #pragma unroll
    for (int i = 0; i < 4; i++) pr[i] = *(const ush4*)(nxim + pAddr[i]);
    #pragma unroll
    for (int i = 0; i < 3; i++) wr[i] = *(const sh8*)(wbf + wAddr[i]);

    for (int ch = 0; ch < 3; ch++){
        __syncthreads();
        #pragma unroll
        for (int i = 0; i < 4; i++) *(ush4*)&pt[pOff[i]] = pr[i];
        #pragma unroll
        for (int i = 0; i < 3; i++) *(sh8*)&wt[wOff[i]] = wr[i];
        if (ch < 2){
            #pragma unroll
            for (int i = 0; i < 4; i++){ pAddr[i] += cinc; pr[i] = *(const ush4*)(nxim + pAddr[i]); }
            #pragma unroll
            for (int i = 0; i < 3; i++){ wAddr[i] += 64;  wr[i] = *(const sh8*)(wbf + wAddr[i]); }
        }
        __syncthreads();

        sh8 a0 = *(const sh8*)&pt[(wid*16 + lo)*72 + g*8];
        sh8 a1 = *(const sh8*)&pt[(wid*16 + lo)*72 + 32 + g*8];
        #pragma unroll
        for (int ct = 0; ct < 6; ct++){
            sh8 b0 = *(const sh8*)&wt[(ct*16 + lo)*72 + g*8];
            sh8 b1 = *(const sh8*)&wt[(ct*16 + lo)*72 + 32 + g*8];
            acc[ct] = __builtin_amdgcn_mfma_f32_16x16x32_bf16(a0, b0, acc[ct], 0, 0, 0);
            acc[ct] = __builtin_amdgcn_mfma_f32_16x16x32_bf16(a1, b1, acc[ct], 0, 0, 0);
        }
    }

    int rowsTotal = NB << posLog;
    #pragma unroll
    for (int ct = 0; ct < 6; ct++){
        int o = ct*16 + lo;
        #pragma unroll
        for (int jx = 0; jx < 4; jx++){
            int R = rb*64 + wid*16 + g*4 + jx;
            part[((size_t)split*rowsTotal + R)*96 + o] = acc[ct][jx];
        }
    }
}

// ---------------- 4. reduce K-splits + bias + LN + gelu + Z/q/k -> bf16 qp/ktp ----------------
__global__ __launch_bounds__(64) void k_reduce(const float* __restrict__ part,
                                               int nsplit, int rows, int Mper,
                                               const float* __restrict__ cbias,
                                               const float* __restrict__ lw,
                                               const float* __restrict__ lb,
                                               const float* __restrict__ wqk,
                                               const float* __restrict__ bqk,
                                               const float* __restrict__ g,
                                               const float* __restrict__ be,
                                               unsigned short* __restrict__ qp,
                                               unsigned short* __restrict__ ktp){
    __shared__ float xsh[96];
    int row = blockIdx.x;
    int l = threadIdx.x;
    float y1 = 0.0f, y2 = 0.0f;
    for (int s = 0; s < nsplit; s++){
        const float* pr = part + ((size_t)s*rows + row)*96;
        y1 += pr[l];
        if (l < 32) y2 += pr[64+l];
    }
    y1 += cbias[l];
    if (l < 32) y2 += cbias[64+l];
    float s = wave_sum64(y1 + ((l < 32) ? y2 : 0.0f));
    float m = s * (1.0f/96.0f);
    float d1 = y1 - m, d2 = y2 - m;
    float var = wave_sum64(d1*d1 + ((l < 32) ? d2*d2 : 0.0f)) * (1.0f/96.0f);
    float rstd = rsqrtf(var + EPSF);
    xsh[l] = geluf(d1*rstd*lw[l] + lb[l]);
    if (l < 32) xsh[64+l] = geluf(d2*rstd*lw[64+l] + lb[64+l]);
    __syncthreads();
    if (l < 48){
        float z = bqk[l];
        #pragma unroll 4
        for (int c = 0; c < 96; c++) z += xsh[c]*wqk[c*48 + l];
        z = siluf(z);
        float qv = z*g[l]    + be[l];
        float kv = z*g[48+l] + be[48+l];
        int b = row / Mper, p = row - b*Mper;
        qp[(size_t)row*64 + l] = f2bf(qv);
        ktp[((size_t)b*48 + l)*Mper + p] = f2bf(kv);
    } else {
        qp[(size_t)row*64 + l] = 0;      // zero the d-pad
    }
}

// ---------------- 5. attention via bf16 MFMA: swapped QK^T + in-register P (permlane) ----------------
// Block = 128 rows (4 waves x 32 = 2 n-tiles each). Per 32-m chunk:
//   gemm1: S^T[mt][nt] = mfma(q, v)  -> lane holds P[n=lo][m=mt*16+g*4+j]
//   relu^2 in f32, pack bf16, 2x(swap32+swap16) -> pa[nt] = A-frag P[n=lo][m=g*8..+7]
//   gemm2: acc[nt][dt] += mfma(pa, k^T)   -- zero LDS for P
__global__ __launch_bounds__(256) void k_attn(const float* __restrict__ vbuf,
                                              const unsigned short* __restrict__ qp1,
                                              const unsigned short* __restrict__ ktp1,
                                              const unsigned short* __restrict__ qp2,
                                              const unsigned short* __restrict__ ktp2,
                                              float* __restrict__ V1,
                                              float* __restrict__ V2){
    __shared__ unsigned short qs[32*72];    // q[m][d] chunk, stride 72
    __shared__ unsigned short ks[48*72];    // kT[d][m] chunk, stride 72

    int bx   = blockIdx.x;
    int kind = bx >> 9;                 // 0: branch1 (M=256), 1: branch2 (M=1024)
    int blk  = bx & 511;
    int tid  = threadIdx.x;
    int wid  = tid >> 6;
    int lane = tid & 63;
    int lo   = lane & 15;
    int g    = lane >> 4;
    int row0 = blk*128 + wid*32;        // wave's first global row
    int b    = row0 >> 14;              // batch

    int   M    = kind ? 1024 : 256;
    const unsigned short* qp = (kind ? qp2 : qp1) + (size_t)b*M*64;
    const unsigned short* kt = (kind ? ktp2 : ktp1) + (size_t)b*48*M;
    int   voff = kind ? 48 : 0;
    float* vout = kind ? V2 : V1;

    // v B-fragments for 2 n-tiles: lane-lo <-> col n = row0+nt*16+lo, k = d = kc*32+g*8
    sh8 vb[2][2];
    #pragma unroll
    for (int nt = 0; nt < 2; nt++){
        const float* vrow = vbuf + (size_t)(row0 + nt*16 + lo)*CC + voff;
        union { unsigned u[4]; sh8 v; } pk;
        f32x4 a0 = *(const f32x4*)(vrow + g*8);
        f32x4 a1 = *(const f32x4*)(vrow + g*8 + 4);
        pk.u[0] = pack2(a0[0], a0[1]); pk.u[1] = pack2(a0[2], a0[3]);
        pk.u[2] = pack2(a1[0], a1[1]); pk.u[3] = pack2(a1[2], a1[3]);
        vb[nt][0] = pk.v;
        if (g < 2){
            f32x4 b0 = *(const f32x4*)(vrow + 32 + g*8);
            f32x4 b1 = *(const f32x4*)(vrow + 32 + g*8 + 4);
            pk.u[0] = pack2(b0[0], b0[1]); pk.u[1] = pack2(b0[2], b0[3]);
            pk.u[2] = pack2(b1[0], b1[1]); pk.u[3] = pack2(b1[2], b1[3]);
        } else { pk.u[0]=0u; pk.u[1]=0u; pk.u[2]=0u; pk.u[3]=0u; }
        vb[nt][1] = pk.v;
    }

    // staging mapping: q: 256 thr x 16B; k: 192 thr x 16B
    int qm = tid >> 3, qj = tid & 7;
    int kd = tid >> 2, kj = tid & 3;
    bool kact = tid < 192;

    f32x4 acc[2][3];
    #pragma unroll
    for (int nt = 0; nt < 2; nt++)
        #pragma unroll
        for (int dt = 0; dt < 3; dt++) acc[nt][dt] = (f32x4){0.f,0.f,0.f,0.f};

    int nchunk = M >> 5;
    sh8 qreg = *(const sh8*)(qp + (size_t)qm*64 + qj*8);
    sh8 kreg;
    if (kact) kreg = *(const sh8*)(kt + (size_t)kd*M + kj*8);

    for (int ch = 0; ch < nchunk; ch++){
        __syncthreads();                 // WAR on qs/ks
        *(sh8*)&qs[qm*72 + qj*8] = qreg;
        if (kact) *(sh8*)&ks[kd*72 + kj*8] = kreg;
        if (ch + 1 < nchunk){            // prefetch next chunk under compute
            int mb2 = (ch + 1)*32;
            qreg = *(const sh8*)(qp + (size_t)(mb2 + qm)*64 + qj*8);
            if (kact) kreg = *(const sh8*)(kt + (size_t)kd*M + mb2 + kj*8);
        }
        __syncthreads();

        // ---- gemm1 (swapped): c[mt][nt] = S^T tile, rows m, cols n ----
        sh8 aq[2][2];
        #pragma unroll
        for (int mt = 0; mt < 2; mt++)
            #pragma unroll
            for (int kc = 0; kc < 2; kc++)
                aq[mt][kc] = *(const sh8*)&qs[(mt*16 + lo)*72 + kc*32 + g*8];
        f32x4 c00, c01, c10, c11;
        c00 = (f32x4){0.f,0.f,0.f,0.f}; c01 = c00; c10 = c00; c11 = c00;
        c00 = __builtin_amdgcn_mfma_f32_16x16x32_bf16(aq[0][0], vb[0][0], c00, 0,0,0);
        c00 = __builtin_amdgcn_mfma_f32_16x16x32_bf16(aq[0][1], vb[0][1], c00, 0,0,0);
        c01 = __builtin_amdgcn_mfma_f32_16x16x32_bf16(aq[0][0], vb[1][0], c01, 0,0,0);
        c01 = __builtin_amdgcn_mfma_f32_16x16x32_bf16(aq[0][1], vb[1][1], c01, 0,0,0);
        c10 = __builtin_amdgcn_mfma_f32_16x16x32_bf16(aq[1][0], vb[0][0], c10, 0,0,0);
        c10 = __builtin_amdgcn_mfma_f32_16x16x32_bf16(aq[1][1], vb[0][1], c10, 0,0,0);
        c11 = __builtin_amdgcn_mfma_f32_16x16x32_bf16(aq[1][0], vb[1][0], c11, 0,0,0);
        c11 = __builtin_amdgcn_mfma_f32_16x16x32_bf16(aq[1][1], vb[1][1], c11, 0,0,0);

        // ---- P = relu(S/N)^2, pack, permlane redistribute -> pa[nt] ----
        sh8 pa[2];
        #pragma unroll
        for (int nt = 0; nt < 2; nt++){
            f32x4 cm0 = nt ? c01 : c00;   // mt=0 tile for this nt
            f32x4 cm1 = nt ? c11 : c10;   // mt=1 tile
            float p00 = fmaxf(cm0[0]*INV_N, 0.f); p00 *= p00;
            float p01 = fmaxf(cm0[1]*INV_N, 0.f); p01 *= p01;
            float p02 = fmaxf(cm0[2]*INV_N, 0.f); p02 *= p02;
            float p03 = fmaxf(cm0[3]*INV_N, 0.f); p03 *= p03;
            float p10 = fmaxf(cm1[0]*INV_N, 0.f); p10 *= p10;
            float p11 = fmaxf(cm1[1]*INV_N, 0.f); p11 *= p11;
            float p12 = fmaxf(cm1[2]*INV_N, 0.f); p12 *= p12;
            float p13 = fmaxf(cm1[3]*INV_N, 0.f); p13 *= p13;
            unsigned a0 = pack2(p00, p01);   // mt0, j01
            unsigned a1 = pack2(p02, p03);   // mt0, j23
            unsigned b0 = pack2(p10, p11);   // mt1, j01
            unsigned b1 = pack2(p12, p13);   // mt1, j23
            swap32(a0, b0); swap16(a0, b0);  // -> a0=W0, b0=W2
            swap32(a1, b1); swap16(a1, b1);  // -> a1=W1, b1=W3
            union { unsigned u[4]; sh8 v; } pk;
            pk.u[0] = a0; pk.u[1] = a1; pk.u[2] = b0; pk.u[3] = b1;
            pa[nt] = pk.v;
        }

        // ---- gemm2: acc[nt][dt] += P . k (bk shared across nt) ----
        #pragma unroll
        for (int dt = 0; dt < 3; dt++){
            sh8 bk = *(const sh8*)&ks[(dt*16 + lo)*72 + g*8];
            acc[0][dt] = __builtin_amdgcn_mfma_f32_16x16x32_bf16(pa[0], bk, acc[0][dt], 0, 0, 0);
            acc[1][dt] = __builtin_amdgcn_mfma_f32_16x16x32_bf16(pa[1], bk, acc[1][dt], 0, 0, 0);
        }
    }

    // ---- write O: row = row0 + nt*16 + g*4 + j, col = dt*16 + lo ----
    #pragma unroll
    for (int nt = 0; nt < 2; nt++)
        #pragma unroll
        for (int dt = 0; dt < 3; dt++)
            #pragma unroll
            for (int j = 0; j < 4; j++)
                vout[(size_t)(row0 + nt*16 + g*4 + j)*48 + dt*16 + lo] = acc[nt][dt][j];
}

// ---------------- 6. final via bf16 MFMA: out = (xc*gate)@proj + projb + xc ----------------
__global__ __launch_bounds__(256) void k_final(const float* __restrict__ V1,
                                               const float* __restrict__ V2,
                                               const float* __restrict__ gate,
                                               const float* __restrict__ projw,
                                               const float* __restrict__ projb,
                                               float* __restrict__ out){
    __shared__ unsigned short pjbf[96*100];    // [col][k] bf16, stride 100
    int tid  = threadIdx.x;
    int lane = tid & 63;
    int wid  = tid >> 6;
    int lo   = lane & 15;
    int g    = lane >> 4;
    int row0 = blockIdx.x*64 + wid*16;

    #pragma unroll
    for (int it = 0; it < 36; it++){
        int idx = tid + it*256;          // 0..9215
        int k = idx / 96, col = idx - k*96;
        pjbf[col*100 + k] = f2bf(projw[idx]);
    }

    sh8 a[3];
    {
        size_t row = row0 + lo;
        const float* gr = gate + row*CC;
        #pragma unroll
        for (int kc = 0; kc < 3; kc++){
            int d0 = kc*32 + g*8;
            const float* xsrc = (d0 < 48) ? (V1 + row*48 + d0) : (V2 + row*48 + d0 - 48);
            f32x4 x0 = *(const f32x4*)xsrc;
            f32x4 x1 = *(const f32x4*)(xsrc + 4);
            f32x4 g0 = *(const f32x4*)(gr + d0);
            f32x4 g1 = *(const f32x4*)(gr + d0 + 4);
            union { unsigned u[4]; sh8 v; } pk;
            pk.u[0] = pack2(x0[0]*g0[0], x0[1]*g0[1]);
            pk.u[1] = pack2(x0[2]*g0[2], x0[3]*g0[3]);
            pk.u[2] = pack2(x1[0]*g1[0], x1[1]*g1[1]);
            pk.u[3] = pack2(x1[2]*g1[2], x1[3]*g1[3]);
            a[kc] = pk.v;
        }
    }
    __syncthreads();

    f32x4 acc[6];
    #pragma unroll
    for (int ct = 0; ct < 6; ct++) acc[ct] = (f32x4){0.f,0.f,0.f,0.f};
    #pragma unroll
    for (int ct = 0; ct < 6; ct++){
        #pragma unroll
        for (int kc = 0; kc < 3; kc++){
            sh8 bw = *(const sh8*)&pjbf[(ct*16 + lo)*100 + kc*32 + g*8];
            acc[ct] = __builtin_amdgcn_mfma_f32_16x16x32_bf16(a[kc], bw, acc[ct], 0, 0, 0);
        }
    }

    #pragma unroll
    for (int ct = 0; ct < 6; ct++){
        int col = ct*16 + lo;
        float bcol = projb[col];
        const float* xsrc = (ct < 3) ? (V1 + col) : (V2 + col - 48);
        #pragma unroll
        for (int j = 0; j < 4; j++){
            size_t row = row0 + g*4 + j;
            float xc = xsrc[row*48];
            out[row*CC + col] = acc[ct][j] + bcol + xc;
        }
    }
}

extern "C" void kernel_launch(void* const* d_in, const int* in_sizes, int n_in,
                              void* d_out, int out_size, void* d_ws, size_t ws_size,
                              hipStream_t stream){
    const float* x      = (const float*)d_in[0];
    const float* norm_w = (const float*)d_in[3];
    const float* norm_b = (const float*)d_in[4];
    const float* Wh     = (const float*)d_in[5];
    const float* bh     = (const float*)d_in[6];
    const float* Wqk    = (const float*)d_in[7];
    const float* bqk    = (const float*)d_in[8];
    const float* g1     = (const float*)d_in[9];
    const float* be1    = (const float*)d_in[10];
    const float* g2     = (const float*)d_in[11];
    const float* be2    = (const float*)d_in[12];
    const float* sr1_w  = (const float*)d_in[13];
    const float* sr1_b  = (const float*)d_in[14];
    const float* sr2_w  = (const float*)d_in[15];
    const float* sr2_b  = (const float*)d_in[16];
    const float* n1_w   = (const float*)d_in[17];
    const float* n1_b   = (const float*)d_in[18];
    const float* n2_w   = (const float*)d_in[19];
    const float* n2_b   = (const float*)d_in[20];
    const float* proj_w = (const float*)d_in[21];
    const float* proj_b = (const float*)d_in[22];
    float* out = (float*)d_out;

    float* ws = (float*)d_ws;
    size_t off = 0;
    unsigned short* nxbf = (unsigned short*)(ws + off); off += (size_t)NB*NTOK*CC/2;
    unsigned short* nxim = (unsigned short*)(ws + off); off += (size_t)NB*NTOK*CC/2;
    unsigned short* w1bf = (unsigned short*)(ws + off); off += (size_t)96*6144/2;
    unsigned short* w2bf = (unsigned short*)(ws + off); off += (size_t)96*1536/2;
    float* vbuf = ws + off; off += (size_t)NB*NTOK*CC;
    float* gate = ws + off; off += (size_t)NB*NTOK*CC;
    unsigned short* qp1 = (unsigned short*)(ws + off); off += (size_t)NB*256*64/2;
    unsigned short* kt1 = (unsigned short*)(ws + off); off += (size_t)NB*48*256/2;
    unsigned short* qp2 = (unsigned short*)(ws + off); off += (size_t)NB*1024*64/2;
    unsigned short* kt2 = (unsigned short*)(ws + off); off += (size_t)NB*48*1024/2;
    float* part1= ws + off; off += (size_t)32*NB*256*96;
    float* part2= ws + off; off += (size_t)8*NB*1024*96;
    float* V1   = ws + off; off += (size_t)NB*NTOK*48;
    float* V2   = ws + off; off += (size_t)NB*NTOK*48;
    if (ws_size < off*sizeof(float)) return;

    k_cvt  <<<720, 256, 0, stream>>>(sr1_w, w1bf, 96*6144, sr2_w, w2bf, 96*1536);
    k_ln   <<<16384, 256, 0, stream>>>(x, norm_w, norm_b, nxbf, nxim);
    k_hgemm<<<1024, 256, 0, stream>>>(nxbf, Wh, bh, vbuf, gate);
    k_conv <<<512, 256, 0, stream>>>(nxim, w1bf, part1, 8, 4, 3, 6144, 16);
    k_conv <<<512, 256, 0, stream>>>(nxim, w2bf, part2, 10, 5, 2, 1536, 64);
    k_reduce<<<1024, 64, 0, stream>>>(part1, 32, 1024, 256, sr1_b, n1_w, n1_b, Wqk, bqk, g1, be1, qp1, kt1);
    k_reduce<<<4096, 64, 0, stream>>>(part2, 8, 4096, 1024, sr2_b, n2_w, n2_b, Wqk, bqk, g2, be2, qp2, kt2);
    k_attn <<<1024, 256, 0, stream>>>(vbuf, qp1, kt1, qp2, kt2, V1, V2);
    k_final<<<1024, 256, 0, stream>>>(V1, V2, gate, proj_w, proj_b, out);
}

// Round 12
// 141.192 us; speedup vs baseline: 2.2364x; 1.0234x over previous
//
#include <hip/hip_runtime.h>
#include <math.h>

#define NB   4
#define IH   128
#define IW   128
#define NTOK 16384        // IH*IW
#define CC   96
#define HID  192
#define QKD  48
#define EPSF 1e-5f
#define INV_N (1.0f/16384.0f)

typedef __attribute__((ext_vector_type(8))) short sh8;    // 8 bf16 (4 VGPRs)
typedef __attribute__((ext_vector_type(4))) short ush4;   // 4 bf16 (2 VGPRs)
typedef __attribute__((ext_vector_type(4))) float f32x4;  // 4 fp32

__device__ __forceinline__ float wave_sum64(float v){
    #pragma unroll
    for (int off = 32; off > 0; off >>= 1) v += __shfl_xor(v, off, 64);
    return v;
}
__device__ __forceinline__ float siluf(float x){ return x / (1.0f + __expf(-x)); }
__device__ __forceinline__ float geluf(float x){ return 0.5f*x*(1.0f + erff(x*0.7071067811865475f)); }

__device__ __forceinline__ unsigned short f2bf(float f){   // RNE float->bf16 bits
    union { float f; unsigned u; } x; x.f = f;
    unsigned u = x.u + 0x7FFFu + ((x.u >> 16) & 1u);
    return (unsigned short)(u >> 16);
}
__device__ __forceinline__ unsigned pack2(float a, float b){
    return (unsigned)f2bf(a) | ((unsigned)f2bf(b) << 16);
}
// HW packed f32x2 -> bf16x2 (dst.lo = bf16(a), dst.hi = bf16(b)) — 1 VALU instr
__device__ __forceinline__ unsigned cvtpk(float a, float b){
    unsigned r;
    asm("v_cvt_pk_bf16_f32 %0, %1, %2" : "=v"(r) : "v"(a), "v"(b));
    return r;
}
// gfx950 cross-lane half-swaps (both operands modified)
__device__ __forceinline__ void swap32(unsigned &x, unsigned &y){
    asm volatile("v_permlane32_swap_b32 %0, %1" : "+v"(x), "+v"(y));
}
__device__ __forceinline__ void swap16(unsigned &x, unsigned &y){
    asm volatile("v_permlane16_swap_b32 %0, %1" : "+v"(x), "+v"(y));
}

// ---------------- 0. one-off: conv weights fp32 -> bf16 ----------------
__global__ __launch_bounds__(256) void k_cvt(const float* __restrict__ s1, unsigned short* __restrict__ d1, int n1,
                                             const float* __restrict__ s2, unsigned short* __restrict__ d2, int n2){
    int i4 = (blockIdx.x*256 + threadIdx.x)*4;
    if (i4 < n1){
        float4 v = *(const float4*)(s1 + i4);
        ush4 o = {(short)f2bf(v.x), (short)f2bf(v.y), (short)f2bf(v.z), (short)f2bf(v.w)};
        *(ush4*)(d1 + i4) = o;
    } else {
        int j = i4 - n1;
        if (j < n2){
            float4 v = *(const float4*)(s2 + j);
            ush4 o = {(short)f2bf(v.x), (short)f2bf(v.y), (short)f2bf(v.z), (short)f2bf(v.w)};
            *(ush4*)(d2 + j) = o;
        }
    }
}

// ---------------- 1. LayerNorm -> bf16, token-major (nxbf) + image-major (nxim) ----------------
__global__ __launch_bounds__(256) void k_ln(const float* __restrict__ x,
                                            const float* __restrict__ w,
                                            const float* __restrict__ bb,
                                            unsigned short* __restrict__ nxbf,
                                            unsigned short* __restrict__ nxim){
    __shared__ unsigned short tile[4][96];
    int r = threadIdx.x >> 6;
    int row = blockIdx.x*4 + r;
    int l = threadIdx.x & 63;
    const float* xr = x + (size_t)row*CC;
    float a = xr[l];
    float b = (l < 32) ? xr[64+l] : 0.0f;
    float s = wave_sum64(a + b);
    float m = s * (1.0f/96.0f);
    float d1 = a - m;
    float d2 = b - m;
    float sq = d1*d1 + ((l < 32) ? d2*d2 : 0.0f);
    float var = wave_sum64(sq) * (1.0f/96.0f);
    float rstd = rsqrtf(var + EPSF);
    unsigned short b1 = f2bf(d1*rstd*w[l] + bb[l]);
    nxbf[(size_t)row*CC + l] = b1;
    tile[r][l] = b1;
    if (l < 32){
        unsigned short b2 = f2bf(d2*rstd*w[64+l] + bb[64+l]);
        nxbf[(size_t)row*CC + 64 + l] = b2;
        tile[r][64+l] = b2;
    }
    __syncthreads();
    int t = threadIdx.x;
    if (t < 96){
        int row0 = blockIdx.x*4;
        int bb2 = row0 >> 14, hw = row0 & 16383;
        ush4 v = {(short)tile[0][t], (short)tile[1][t], (short)tile[2][t], (short)tile[3][t]};
        *(ush4*)(nxim + (((size_t)(bb2*96 + t)) << 14) + hw) = v;
    }
}

// ---------------- 2. h = silu(nxbf @ Wh + bh) via bf16 MFMA; split v/gate ----------------
__global__ __launch_bounds__(256) void k_hgemm(const unsigned short* __restrict__ nxbf,
                                               const float* __restrict__ Wh,
                                               const float* __restrict__ bh,
                                               float* __restrict__ vbuf,
                                               float* __restrict__ gate){
    __shared__ unsigned short whbf[192*100];   // [col][k] bf16, stride 100
    int tid  = threadIdx.x;
    int lane = tid & 63;
    int wid  = tid >> 6;
    int lo   = lane & 15;
    int g    = lane >> 4;
    int row0 = blockIdx.x*64 + wid*16;

    #pragma unroll
    for (int it = 0; it < 72; it++){
        int idx = tid + it*256;          // 0..18431
        int k = idx / 192, col = idx - k*192;
        whbf[col*100 + k] = f2bf(Wh[idx]);
    }

    sh8 a[3];
    {
        const unsigned short* ar = nxbf + (size_t)(row0 + lo)*CC;
        #pragma unroll
        for (int kc = 0; kc < 3; kc++)
            a[kc] = *(const sh8*)(ar + kc*32 + g*8);
    }
    __syncthreads();

    f32x4 acc[12];
    #pragma unroll
    for (int ct = 0; ct < 12; ct++) acc[ct] = (f32x4){0.f,0.f,0.f,0.f};
    #pragma unroll
    for (int ct = 0; ct < 12; ct++){
        #pragma unroll
        for (int kc = 0; kc < 3; kc++){
            sh8 bw = *(const sh8*)&whbf[(ct*16 + lo)*100 + kc*32 + g*8];
            acc[ct] = __builtin_amdgcn_mfma_f32_16x16x32_bf16(a[kc], bw, acc[ct], 0, 0, 0);
        }
    }

    #pragma unroll
    for (int ct = 0; ct < 12; ct++){
        int col = ct*16 + lo;
        float bcol = bh[col];
        #pragma unroll
        for (int j = 0; j < 4; j++){
            size_t row = row0 + g*4 + j;
            float hv = siluf(acc[ct][j] + bcol);
            if (col < 96) vbuf[row*CC + col] = hv;
            else          gate[row*CC + col - 96] = hv;
        }
    }
}

// ---------------- 3. conv via bf16 MFMA (patch GEMM, K-split, prefetched memcpy staging) ----------------
__global__ __launch_bounds__(256) void k_conv(const unsigned short* __restrict__ nxim,
                                              const unsigned short* __restrict__ wbf,
                                              float* __restrict__ part,
                                              int posLog, int pdimLog, int pszLog,
                                              int kTotal, int rowblocks){
    __shared__ unsigned short pt[64*72];   // [pos][k] stride 72
    __shared__ unsigned short wt[96*72];   // [o][k]  stride 72
    int bx = blockIdx.x;
    int rb = bx % rowblocks;
    int split = bx / rowblocks;
    int tid = threadIdx.x;
    int lane = tid & 63, wid = tid >> 6, lo = lane & 15, g = lane >> 4;
    int psz = 1 << pszLog, pdim = 1 << pdimLog;
    int ksLog = 2*pszLog;
    int kb0 = split * 192;
    int cinc = (64 >> ksLog) << 14;

    int j   = tid & 15;
    int coff = (j*4) >> ksLog;
    int s   = (j*4) & (psz*psz - 1);
    int sy  = s >> pszLog, sx = s & (psz-1);
    int pAddr[4], pOff[4];
    #pragma unroll
    for (int i = 0; i < 4; i++){
        int p = (tid >> 4) + 16*i;
        int R = rb*64 + p;
        int b = R >> posLog, pp = R & ((1 << posLog) - 1);
        int pi = pp >> pdimLog, pj = pp & (pdim-1);
        pAddr[i] = (((b*96 + coff) + (kb0 >> ksLog)) << 14) + (pi*psz + sy)*IW + pj*psz + sx;
        pOff[i]  = p*72 + j*4;
    }
    int jj = tid & 7;
    int wAddr[3], wOff[3];
    #pragma unroll
    for (int i = 0; i < 3; i++){
        int o = (tid >> 3) + 32*i;
        wAddr[i] = o*kTotal + kb0 + jj*8;
        wOff[i]  = o*72 + jj*8;
    }

    f32x4 acc[6];
    #pragma unroll
    for (int ct = 0; ct < 6; ct++) acc[ct] = (f32x4){0.f,0.f,0.f,0.f};

    ush4 pr[4]; sh8 wr[3];
    #pragma unroll
    for (int i = 0; i < 4; i++) pr[i] = *(const ush4*)(nxim + pAddr[i]);
    #pragma unroll
    for (int i = 0; i < 3; i++) wr[i] = *(const sh8*)(wbf + wAddr[i]);

    for (int ch = 0; ch < 3; ch++){
        __syncthreads();
        #pragma unroll
        for (int i = 0; i < 4; i++) *(ush4*)&pt[pOff[i]] = pr[i];
        #pragma unroll
        for (int i = 0; i < 3; i++) *(sh8*)&wt[wOff[i]] = wr[i];
        if (ch < 2){
            #pragma unroll
            for (int i = 0; i < 4; i++){ pAddr[i] += cinc; pr[i] = *(const ush4*)(nxim + pAddr[i]); }
            #pragma unroll
            for (int i = 0; i < 3; i++){ wAddr[i] += 64;  wr[i] = *(const sh8*)(wbf + wAddr[i]); }
        }
        __syncthreads();

        sh8 a0 = *(const sh8*)&pt[(wid*16 + lo)*72 + g*8];
        sh8 a1 = *(const sh8*)&pt[(wid*16 + lo)*72 + 32 + g*8];
        #pragma unroll
        for (int ct = 0; ct < 6; ct++){
            sh8 b0 = *(const sh8*)&wt[(ct*16 + lo)*72 + g*8];
            sh8 b1 = *(const sh8*)&wt[(ct*16 + lo)*72 + 32 + g*8];
            acc[ct] = __builtin_amdgcn_mfma_f32_16x16x32_bf16(a0, b0, acc[ct], 0, 0, 0);
            acc[ct] = __builtin_amdgcn_mfma_f32_16x16x32_bf16(a1, b1, acc[ct], 0, 0, 0);
        }
    }

    int rowsTotal = NB << posLog;
    #pragma unroll
    for (int ct = 0; ct < 6; ct++){
        int o = ct*16 + lo;
        #pragma unroll
        for (int jx = 0; jx < 4; jx++){
            int R = rb*64 + wid*16 + g*4 + jx;
            part[((size_t)split*rowsTotal + R)*96 + o] = acc[ct][jx];
        }
    }
}

// ---------------- 4. reduce K-splits + bias + LN + gelu + Z/q/k -> bf16 qp/ktp ----------------
// qp[b][m][64] bf16, PRE-SCALED by 1/N (attn gemm1 then needs no scale); d pad 48..63 = 0.
// ktp[b][d][m] bf16 (pre-transposed for attn gemm2).
__global__ __launch_bounds__(64) void k_reduce(const float* __restrict__ part,
                                               int nsplit, int rows, int Mper,
                                               const float* __restrict__ cbias,
                                               const float* __restrict__ lw,
                                               const float* __restrict__ lb,
                                               const float* __restrict__ wqk,
                                               const float* __restrict__ bqk,
                                               const float* __restrict__ g,
                                               const float* __restrict__ be,
                                               unsigned short* __restrict__ qp,
                                               unsigned short* __restrict__ ktp){
    __shared__ float xsh[96];
    int row = blockIdx.x;
    int l = threadIdx.x;
    float y1 = 0.0f, y2 = 0.0f;
    for (int s = 0; s < nsplit; s++){
        const float* pr = part + ((size_t)s*rows + row)*96;
        y1 += pr[l];
        if (l < 32) y2 += pr[64+l];
    }
    y1 += cbias[l];
    if (l < 32) y2 += cbias[64+l];
    float s = wave_sum64(y1 + ((l < 32) ? y2 : 0.0f));
    float m = s * (1.0f/96.0f);
    float d1 = y1 - m, d2 = y2 - m;
    float var = wave_sum64(d1*d1 + ((l < 32) ? d2*d2 : 0.0f)) * (1.0f/96.0f);
    float rstd = rsqrtf(var + EPSF);
    xsh[l] = geluf(d1*rstd*lw[l] + lb[l]);
    if (l < 32) xsh[64+l] = geluf(d2*rstd*lw[64+l] + lb[64+l]);
    __syncthreads();
    if (l < 48){
        float z = bqk[l];
        #pragma unroll 4
        for (int c = 0; c < 96; c++) z += xsh[c]*wqk[c*48 + l];
        z = siluf(z);
        float qv = (z*g[l]    + be[l]) * INV_N;   // fold 1/N into q
        float kv =  z*g[48+l] + be[48+l];
        int b = row / Mper, p = row - b*Mper;
        qp[(size_t)row*64 + l] = f2bf(qv);
        ktp[((size_t)b*48 + l)*Mper + p] = f2bf(kv);
    } else {
        qp[(size_t)row*64 + l] = 0;      // zero the d-pad
    }
}

// ---------------- 5. attention via bf16 MFMA: swapped QK^T + in-register P (permlane) ----------------
// Double-buffered LDS -> ONE barrier per chunk; P pack via v_cvt_pk_bf16_f32; q pre-scaled by 1/N.
__global__ __launch_bounds__(256) void k_attn(const float* __restrict__ vbuf,
                                              const unsigned short* __restrict__ qp1,
                                              const unsigned short* __restrict__ ktp1,
                                              const unsigned short* __restrict__ qp2,
                                              const unsigned short* __restrict__ ktp2,
                                              float* __restrict__ V1,
                                              float* __restrict__ V2){
    __shared__ unsigned short qs[2][32*72];    // q[m][d] chunk, stride 72
    __shared__ unsigned short ks[2][48*72];    // kT[d][m] chunk, stride 72

    int bx   = blockIdx.x;
    int kind = bx >> 9;                 // 0: branch1 (M=256), 1: branch2 (M=1024)
    int blk  = bx & 511;
    int tid  = threadIdx.x;
    int wid  = tid >> 6;
    int lane = tid & 63;
    int lo   = lane & 15;
    int g    = lane >> 4;
    int row0 = blk*128 + wid*32;        // wave's first global row
    int b    = row0 >> 14;              // batch

    int   M    = kind ? 1024 : 256;
    const unsigned short* qp = (kind ? qp2 : qp1) + (size_t)b*M*64;
    const unsigned short* kt = (kind ? ktp2 : ktp1) + (size_t)b*48*M;
    int   voff = kind ? 48 : 0;
    float* vout = kind ? V2 : V1;

    // v B-fragments for 2 n-tiles
    sh8 vb[2][2];
    #pragma unroll
    for (int nt = 0; nt < 2; nt++){
        const float* vrow = vbuf + (size_t)(row0 + nt*16 + lo)*CC + voff;
        union { unsigned u[4]; sh8 v; } pk;
        f32x4 a0 = *(const f32x4*)(vrow + g*8);
        f32x4 a1 = *(const f32x4*)(vrow + g*8 + 4);
        pk.u[0] = cvtpk(a0[0], a0[1]); pk.u[1] = cvtpk(a0[2], a0[3]);
        pk.u[2] = cvtpk(a1[0], a1[1]); pk.u[3] = cvtpk(a1[2], a1[3]);
        vb[nt][0] = pk.v;
        if (g < 2){
            f32x4 b0 = *(const f32x4*)(vrow + 32 + g*8);
            f32x4 b1 = *(const f32x4*)(vrow + 32 + g*8 + 4);
            pk.u[0] = cvtpk(b0[0], b0[1]); pk.u[1] = cvtpk(b0[2], b0[3]);
            pk.u[2] = cvtpk(b1[0], b1[1]); pk.u[3] = cvtpk(b1[2], b1[3]);
        } else { pk.u[0]=0u; pk.u[1]=0u; pk.u[2]=0u; pk.u[3]=0u; }
        vb[nt][1] = pk.v;
    }

    int qm = tid >> 3, qj = tid & 7;
    int kd = tid >> 2, kj = tid & 3;
    bool kact = tid < 192;

    f32x4 acc[2][3];
    #pragma unroll
    for (int nt = 0; nt < 2; nt++)
        #pragma unroll
        for (int dt = 0; dt < 3; dt++) acc[nt][dt] = (f32x4){0.f,0.f,0.f,0.f};

    int nchunk = M >> 5;
    sh8 qreg = *(const sh8*)(qp + (size_t)qm*64 + qj*8);
    sh8 kreg;
    if (kact) kreg = *(const sh8*)(kt + (size_t)kd*M + kj*8);

    for (int ch = 0; ch < nchunk; ch++){
        int bs = ch & 1;
        unsigned short* qb = qs[bs];
        unsigned short* kb = ks[bs];
        *(sh8*)&qb[qm*72 + qj*8] = qreg;
        if (kact) *(sh8*)&kb[kd*72 + kj*8] = kreg;
        __syncthreads();                 // single barrier: stage visible; dbuf handles WAR
        if (ch + 1 < nchunk){            // prefetch next chunk under compute
            int mb2 = (ch + 1)*32;
            qreg = *(const sh8*)(qp + (size_t)(mb2 + qm)*64 + qj*8);
            if (kact) kreg = *(const sh8*)(kt + (size_t)kd*M + mb2 + kj*8);
        }

        // ---- gemm1 (swapped): S^T tiles; q pre-scaled by 1/N ----
        sh8 aq[2][2];
        #pragma unroll
        for (int mt = 0; mt < 2; mt++)
            #pragma unroll
            for (int kc = 0; kc < 2; kc++)
                aq[mt][kc] = *(const sh8*)&qb[(mt*16 + lo)*72 + kc*32 + g*8];
        f32x4 c00, c01, c10, c11;
        c00 = (f32x4){0.f,0.f,0.f,0.f}; c01 = c00; c10 = c00; c11 = c00;
        c00 = __builtin_amdgcn_mfma_f32_16x16x32_bf16(aq[0][0], vb[0][0], c00, 0,0,0);
        c00 = __builtin_amdgcn_mfma_f32_16x16x32_bf16(aq[0][1], vb[0][1], c00, 0,0,0);
        c01 = __builtin_amdgcn_mfma_f32_16x16x32_bf16(aq[0][0], vb[1][0], c01, 0,0,0);
        c01 = __builtin_amdgcn_mfma_f32_16x16x32_bf16(aq[0][1], vb[1][1], c01, 0,0,0);
        c10 = __builtin_amdgcn_mfma_f32_16x16x32_bf16(aq[1][0], vb[0][0], c10, 0,0,0);
        c10 = __builtin_amdgcn_mfma_f32_16x16x32_bf16(aq[1][1], vb[0][1], c10, 0,0,0);
        c11 = __builtin_amdgcn_mfma_f32_16x16x32_bf16(aq[1][0], vb[1][0], c11, 0,0,0);
        c11 = __builtin_amdgcn_mfma_f32_16x16x32_bf16(aq[1][1], vb[1][1], c11, 0,0,0);

        // ---- P = relu(S)^2 (scale pre-folded), cvt_pk, permlane redistribute ----
        sh8 pa[2];
        #pragma unroll
        for (int nt = 0; nt < 2; nt++){
            f32x4 cm0 = nt ? c01 : c00;
            f32x4 cm1 = nt ? c11 : c10;
            float p00 = fmaxf(cm0[0], 0.f); p00 *= p00;
            float p01 = fmaxf(cm0[1], 0.f); p01 *= p01;
            float p02 = fmaxf(cm0[2], 0.f); p02 *= p02;
            float p03 = fmaxf(cm0[3], 0.f); p03 *= p03;
            float p10 = fmaxf(cm1[0], 0.f); p10 *= p10;
            float p11 = fmaxf(cm1[1], 0.f); p11 *= p11;
            float p12 = fmaxf(cm1[2], 0.f); p12 *= p12;
            float p13 = fmaxf(cm1[3], 0.f); p13 *= p13;
            unsigned a0 = cvtpk(p00, p01);   // mt0, j01
            unsigned a1 = cvtpk(p02, p03);   // mt0, j23
            unsigned b0 = cvtpk(p10, p11);   // mt1, j01
            unsigned b1 = cvtpk(p12, p13);   // mt1, j23
            swap32(a0, b0); swap16(a0, b0);  // -> a0=W0, b0=W2
            swap32(a1, b1); swap16(a1, b1);  // -> a1=W1, b1=W3
            union { unsigned u[4]; sh8 v; } pk;
            pk.u[0] = a0; pk.u[1] = a1; pk.u[2] = b0; pk.u[3] = b1;
            pa[nt] = pk.v;
        }

        // ---- gemm2: acc[nt][dt] += P . k ----
        #pragma unroll
        for (int dt = 0; dt < 3; dt++){
            sh8 bk = *(const sh8*)&kb[(dt*16 + lo)*72 + g*8];
            acc[0][dt] = __builtin_amdgcn_mfma_f32_16x16x32_bf16(pa[0], bk, acc[0][dt], 0, 0, 0);
            acc[1][dt] = __builtin_amdgcn_mfma_f32_16x16x32_bf16(pa[1], bk, acc[1][dt], 0, 0, 0);
        }
    }

    #pragma unroll
    for (int nt = 0; nt < 2; nt++)
        #pragma unroll
        for (int dt = 0; dt < 3; dt++)
            #pragma unroll
            for (int j = 0; j < 4; j++)
                vout[(size_t)(row0 + nt*16 + g*4 + j)*48 + dt*16 + lo] = acc[nt][dt][j];
}

// ---------------- 6. final via bf16 MFMA: out = (xc*gate)@proj + projb + xc ----------------
__global__ __launch_bounds__(256) void k_final(const float* __restrict__ V1,
                                               const float* __restrict__ V2,
                                               const float* __restrict__ gate,
                                               const float* __restrict__ projw,
                                               const float* __restrict__ projb,
                                               float* __restrict__ out){
    __shared__ unsigned short pjbf[96*100];    // [col][k] bf16, stride 100
    int tid  = threadIdx.x;
    int lane = tid & 63;
    int wid  = tid >> 6;
    int lo   = lane & 15;
    int g    = lane >> 4;
    int row0 = blockIdx.x*64 + wid*16;

    #pragma unroll
    for (int it = 0; it < 36; it++){
        int idx = tid + it*256;          // 0..9215
        int k = idx / 96, col = idx - k*96;
        pjbf[col*100 + k] = f2bf(projw[idx]);
    }

    sh8 a[3];
    {
        size_t row = row0 + lo;
        const float* gr = gate + row*CC;
        #pragma unroll
        for (int kc = 0; kc < 3; kc++){
            int d0 = kc*32 + g*8;
            const float* xsrc = (d0 < 48) ? (V1 + row*48 + d0) : (V2 + row*48 + d0 - 48);
            f32x4 x0 = *(const f32x4*)xsrc;
            f32x4 x1 = *(const f32x4*)(xsrc + 4);
            f32x4 g0 = *(const f32x4*)(gr + d0);
            f32x4 g1 = *(const f32x4*)(gr + d0 + 4);
            union { unsigned u[4]; sh8 v; } pk;
            pk.u[0] = cvtpk(x0[0]*g0[0], x0[1]*g0[1]);
            pk.u[1] = cvtpk(x0[2]*g0[2], x0[3]*g0[3]);
            pk.u[2] = cvtpk(x1[0]*g1[0], x1[1]*g1[1]);
            pk.u[3] = cvtpk(x1[2]*g1[2], x1[3]*g1[3]);
            a[kc] = pk.v;
        }
    }
    __syncthreads();

    f32x4 acc[6];
    #pragma unroll
    for (int ct = 0; ct < 6; ct++) acc[ct] = (f32x4){0.f,0.f,0.f,0.f};
    #pragma unroll
    for (int ct = 0; ct < 6; ct++){
        #pragma unroll
        for (int kc = 0; kc < 3; kc++){
            sh8 bw = *(const sh8*)&pjbf[(ct*16 + lo)*100 + kc*32 + g*8];
            acc[ct] = __builtin_amdgcn_mfma_f32_16x16x32_bf16(a[kc], bw, acc[ct], 0, 0, 0);
        }
    }

    #pragma unroll
    for (int ct = 0; ct < 6; ct++){
        int col = ct*16 + lo;
        float bcol = projb[col];
        const float* xsrc = (ct < 3) ? (V1 + col) : (V2 + col - 48);
        #pragma unroll
        for (int j = 0; j < 4; j++){
            size_t row = row0 + g*4 + j;
            float xc = xsrc[row*48];
            out[row*CC + col] = acc[ct][j] + bcol + xc;
        }
    }
}

extern "C" void kernel_launch(void* const* d_in, const int* in_sizes, int n_in,
                              void* d_out, int out_size, void* d_ws, size_t ws_size,
                              hipStream_t stream){
    const float* x      = (const float*)d_in[0];
    const float* norm_w = (const float*)d_in[3];
    const float* norm_b = (const float*)d_in[4];
    const float* Wh     = (const float*)d_in[5];
    const float* bh     = (const float*)d_in[6];
    const float* Wqk    = (const float*)d_in[7];
    const float* bqk    = (const float*)d_in[8];
    const float* g1     = (const float*)d_in[9];
    const float* be1    = (const float*)d_in[10];
    const float* g2     = (const float*)d_in[11];
    const float* be2    = (const float*)d_in[12];
    const float* sr1_w  = (const float*)d_in[13];
    const float* sr1_b  = (const float*)d_in[14];
    const float* sr2_w  = (const float*)d_in[15];
    const float* sr2_b  = (const float*)d_in[16];
    const float* n1_w   = (const float*)d_in[17];
    const float* n1_b   = (const float*)d_in[18];
    const float* n2_w   = (const float*)d_in[19];
    const float* n2_b   = (const float*)d_in[20];
    const float* proj_w = (const float*)d_in[21];
    const float* proj_b = (const float*)d_in[22];
    float* out = (float*)d_out;

    float* ws = (float*)d_ws;
    size_t off = 0;
    unsigned short* nxbf = (unsigned short*)(ws + off); off += (size_t)NB*NTOK*CC/2;
    unsigned short* nxim = (unsigned short*)(ws + off); off += (size_t)NB*NTOK*CC/2;
    unsigned short* w1bf = (unsigned short*)(ws + off); off += (size_t)96*6144/2;
    unsigned short* w2bf = (unsigned short*)(ws + off); off += (size_t)96*1536/2;
    float* vbuf = ws + off; off += (size_t)NB*NTOK*CC;
    float* gate = ws + off; off += (size_t)NB*NTOK*CC;
    unsigned short* qp1 = (unsigned short*)(ws + off); off += (size_t)NB*256*64/2;
    unsigned short* kt1 = (unsigned short*)(ws + off); off += (size_t)NB*48*256/2;
    unsigned short* qp2 = (unsigned short*)(ws + off); off += (size_t)NB*1024*64/2;
    unsigned short* kt2 = (unsigned short*)(ws + off); off += (size_t)NB*48*1024/2;
    float* part1= ws + off; off += (size_t)32*NB*256*96;
    float* part2= ws + off; off += (size_t)8*NB*1024*96;
    float* V1   = ws + off; off += (size_t)NB*NTOK*48;
    float* V2   = ws + off; off += (size_t)NB*NTOK*48;
    if (ws_size < off*sizeof(float)) return;

    k_cvt  <<<720, 256, 0, stream>>>(sr1_w, w1bf, 96*6144, sr2_w, w2bf, 96*1536);
    k_ln   <<<16384, 256, 0, stream>>>(x, norm_w, norm_b, nxbf, nxim);
    k_hgemm<<<1024, 256, 0, stream>>>(nxbf, Wh, bh, vbuf, gate);
    k_conv <<<512, 256, 0, stream>>>(nxim, w1bf, part1, 8, 4, 3, 6144, 16);
    k_conv <<<512, 256, 0, stream>>>(nxim, w2bf, part2, 10, 5, 2, 1536, 64);
    k_reduce<<<1024, 64, 0, stream>>>(part1, 32, 1024, 256, sr1_b, n1_w, n1_b, Wqk, bqk, g1, be1, qp1, kt1);
    k_reduce<<<4096, 64, 0, stream>>>(part2, 8, 4096, 1024, sr2_b, n2_w, n2_b, Wqk, bqk, g2, be2, qp2, kt2);
    k_attn <<<1024, 256, 0, stream>>>(vbuf, qp1, kt1, qp2, kt2, V1, V2);
    k_final<<<1024, 256, 0, stream>>>(V1, V2, gate, proj_w, proj_b, out);
}

// Round 13
// 122.008 us; speedup vs baseline: 2.5881x; 1.1572x over previous
//
#include <hip/hip_runtime.h>
#include <math.h>

#define NB   4
#define IH   128
#define IW   128
#define NTOK 16384        // IH*IW
#define CC   96
#define HID  192
#define QKD  48
#define EPSF 1e-5f
#define INV_N (1.0f/16384.0f)

typedef __attribute__((ext_vector_type(8))) short sh8;    // 8 bf16 (4 VGPRs)
typedef __attribute__((ext_vector_type(4))) short ush4;   // 4 bf16 (2 VGPRs)
typedef __attribute__((ext_vector_type(4))) float f32x4;  // 4 fp32

__device__ __forceinline__ float wave_sum64(float v){
    #pragma unroll
    for (int off = 32; off > 0; off >>= 1) v += __shfl_xor(v, off, 64);
    return v;
}
__device__ __forceinline__ float siluf(float x){ return x / (1.0f + __expf(-x)); }
__device__ __forceinline__ float geluf(float x){ return 0.5f*x*(1.0f + erff(x*0.7071067811865475f)); }

__device__ __forceinline__ unsigned short f2bf(float f){   // RNE float->bf16 bits
    union { float f; unsigned u; } x; x.f = f;
    unsigned u = x.u + 0x7FFFu + ((x.u >> 16) & 1u);
    return (unsigned short)(u >> 16);
}
__device__ __forceinline__ float b2f(unsigned hi16){       // bf16 bits (already <<16) -> f32
    union { unsigned u; float f; } c; c.u = hi16; return c.f;
}
// HW packed f32x2 -> bf16x2 (dst.lo = bf16(a), dst.hi = bf16(b)) — 1 VALU instr
__device__ __forceinline__ unsigned cvtpk(float a, float b){
    unsigned r;
    asm("v_cvt_pk_bf16_f32 %0, %1, %2" : "=v"(r) : "v"(a), "v"(b));
    return r;
}
// gfx950 cross-lane half-swaps (both operands modified)
__device__ __forceinline__ void swap32(unsigned &x, unsigned &y){
    asm volatile("v_permlane32_swap_b32 %0, %1" : "+v"(x), "+v"(y));
}
__device__ __forceinline__ void swap16(unsigned &x, unsigned &y){
    asm volatile("v_permlane16_swap_b32 %0, %1" : "+v"(x), "+v"(y));
}

// ---------------- 1. LayerNorm -> bf16 (token-major + image-major) ∥ conv-weight cvt ----------------
// blocks [0,16384): LN; blocks [16384,17104): weight fp32->bf16 conversion
__global__ __launch_bounds__(256) void k_ln(const float* __restrict__ x,
                                            const float* __restrict__ w,
                                            const float* __restrict__ bb,
                                            unsigned short* __restrict__ nxbf,
                                            unsigned short* __restrict__ nxim,
                                            const float* __restrict__ s1, unsigned short* __restrict__ d1, int n1,
                                            const float* __restrict__ s2, unsigned short* __restrict__ d2, int n2){
    int bid = blockIdx.x;
    if (bid >= 16384){
        int i4 = ((bid - 16384)*256 + threadIdx.x)*4;
        if (i4 < n1){
            float4 v = *(const float4*)(s1 + i4);
            unsigned u0 = cvtpk(v.x, v.y), u1 = cvtpk(v.z, v.w);
            ush4 o = {(short)u0, (short)(u0>>16), (short)u1, (short)(u1>>16)};
            *(ush4*)(d1 + i4) = o;
        } else {
            int j = i4 - n1;
            if (j < n2){
                float4 v = *(const float4*)(s2 + j);
                unsigned u0 = cvtpk(v.x, v.y), u1 = cvtpk(v.z, v.w);
                ush4 o = {(short)u0, (short)(u0>>16), (short)u1, (short)(u1>>16)};
                *(ush4*)(d2 + j) = o;
            }
        }
        return;
    }
    __shared__ unsigned short tile[4][96];
    int r = threadIdx.x >> 6;
    int row = bid*4 + r;
    int l = threadIdx.x & 63;
    const float* xr = x + (size_t)row*CC;
    float a = xr[l];
    float b = (l < 32) ? xr[64+l] : 0.0f;
    float s = wave_sum64(a + b);
    float m = s * (1.0f/96.0f);
    float d1f = a - m;
    float d2f = b - m;
    float sq = d1f*d1f + ((l < 32) ? d2f*d2f : 0.0f);
    float var = wave_sum64(sq) * (1.0f/96.0f);
    float rstd = rsqrtf(var + EPSF);
    unsigned short b1 = f2bf(d1f*rstd*w[l] + bb[l]);
    nxbf[(size_t)row*CC + l] = b1;
    tile[r][l] = b1;
    if (l < 32){
        unsigned short b2 = f2bf(d2f*rstd*w[64+l] + bb[64+l]);
        nxbf[(size_t)row*CC + 64 + l] = b2;
        tile[r][64+l] = b2;
    }
    __syncthreads();
    int t = threadIdx.x;
    if (t < 96){
        int row0 = bid*4;
        int bb2 = row0 >> 14, hw = row0 & 16383;
        ush4 v = {(short)tile[0][t], (short)tile[1][t], (short)tile[2][t], (short)tile[3][t]};
        *(ush4*)(nxim + (((size_t)(bb2*96 + t)) << 14) + hw) = v;
    }
}

// ---------------- 2. h = silu(nxbf @ Wh + bh) via bf16 MFMA; v/gate stored bf16 ----------------
__global__ __launch_bounds__(256) void k_hgemm(const unsigned short* __restrict__ nxbf,
                                               const float* __restrict__ Wh,
                                               const float* __restrict__ bh,
                                               unsigned short* __restrict__ vbuf,
                                               unsigned short* __restrict__ gate){
    __shared__ unsigned short whbf[192*100];   // [col][k] bf16, stride 100
    int tid  = threadIdx.x;
    int lane = tid & 63;
    int wid  = tid >> 6;
    int lo   = lane & 15;
    int g    = lane >> 4;
    int row0 = blockIdx.x*64 + wid*16;

    // stage Wh via paired cvt_pk: 9216 col-pairs over [96k][96 colpair]
    #pragma unroll
    for (int it = 0; it < 36; it++){
        int pidx = tid + it*256;
        int k = pidx / 96, cp = (pidx - k*96)*2;
        float2 v = *(const float2*)&Wh[k*HID + cp];
        unsigned u = cvtpk(v.x, v.y);
        whbf[cp*100 + k]     = (unsigned short)u;
        whbf[(cp+1)*100 + k] = (unsigned short)(u >> 16);
    }

    sh8 a[3];
    {
        const unsigned short* ar = nxbf + (size_t)(row0 + lo)*CC;
        #pragma unroll
        for (int kc = 0; kc < 3; kc++)
            a[kc] = *(const sh8*)(ar + kc*32 + g*8);
    }
    __syncthreads();

    f32x4 acc[12];
    #pragma unroll
    for (int ct = 0; ct < 12; ct++) acc[ct] = (f32x4){0.f,0.f,0.f,0.f};
    #pragma unroll
    for (int ct = 0; ct < 12; ct++){
        #pragma unroll
        for (int kc = 0; kc < 3; kc++){
            sh8 bw = *(const sh8*)&whbf[(ct*16 + lo)*100 + kc*32 + g*8];
            acc[ct] = __builtin_amdgcn_mfma_f32_16x16x32_bf16(a[kc], bw, acc[ct], 0, 0, 0);
        }
    }

    #pragma unroll
    for (int ct = 0; ct < 12; ct++){
        int col = ct*16 + lo;
        float bcol = bh[col];
        #pragma unroll
        for (int j = 0; j < 4; j++){
            size_t row = row0 + g*4 + j;
            float hv = siluf(acc[ct][j] + bcol);
            unsigned short hb = (unsigned short)cvtpk(hv, hv);
            if (col < 96) vbuf[row*CC + col] = hb;
            else          gate[row*CC + col - 96] = hb;
        }
    }
}

// ---------------- 3. conv via bf16 MFMA (patch GEMM, K-split, prefetched memcpy staging) ----------------
__global__ __launch_bounds__(256) void k_conv(const unsigned short* __restrict__ nxim,
                                              const unsigned short* __restrict__ wbf,
                                              float* __restrict__ part,
                                              int posLog, int pdimLog, int pszLog,
                                              int kTotal, int rowblocks){
    __shared__ unsigned short pt[64*72];   // [pos][k] stride 72
    __shared__ unsigned short wt[96*72];   // [o][k]  stride 72
    int bx = blockIdx.x;
    int rb = bx % rowblocks;
    int split = bx / rowblocks;
    int tid = threadIdx.x;
    int lane = tid & 63, wid = tid >> 6, lo = lane & 15, g = lane >> 4;
    int psz = 1 << pszLog, pdim = 1 << pdimLog;
    int ksLog = 2*pszLog;
    int kb0 = split * 192;
    int cinc = (64 >> ksLog) << 14;

    int j   = tid & 15;
    int coff = (j*4) >> ksLog;
    int s   = (j*4) & (psz*psz - 1);
    int sy  = s >> pszLog, sx = s & (psz-1);
    int pAddr[4], pOff[4];
    #pragma unroll
    for (int i = 0; i < 4; i++){
        int p = (tid >> 4) + 16*i;
        int R = rb*64 + p;
        int b = R >> posLog, pp = R & ((1 << posLog) - 1);
        int pi = pp >> pdimLog, pj = pp & (pdim-1);
        pAddr[i] = (((b*96 + coff) + (kb0 >> ksLog)) << 14) + (pi*psz + sy)*IW + pj*psz + sx;
        pOff[i]  = p*72 + j*4;
    }
    int jj = tid & 7;
    int wAddr[3], wOff[3];
    #pragma unroll
    for (int i = 0; i < 3; i++){
        int o = (tid >> 3) + 32*i;
        wAddr[i] = o*kTotal + kb0 + jj*8;
        wOff[i]  = o*72 + jj*8;
    }

    f32x4 acc[6];
    #pragma unroll
    for (int ct = 0; ct < 6; ct++) acc[ct] = (f32x4){0.f,0.f,0.f,0.f};

    ush4 pr[4]; sh8 wr[3];
    #pragma unroll
    for (int i = 0; i < 4; i++) pr[i] = *(const ush4*)(nxim + pAddr[i]);
    #pragma unroll
    for (int i = 0; i < 3; i++) wr[i] = *(const sh8*)(wbf + wAddr[i]);

    for (int ch = 0; ch < 3; ch++){
        __syncthreads();
        #pragma unroll
        for (int i = 0; i < 4; i++) *(ush4*)&pt[pOff[i]] = pr[i];
        #pragma unroll
        for (int i = 0; i < 3; i++) *(sh8*)&wt[wOff[i]] = wr[i];
        if (ch < 2){
            #pragma unroll
            for (int i = 0; i < 4; i++){ pAddr[i] += cinc; pr[i] = *(const ush4*)(nxim + pAddr[i]); }
            #pragma unroll
            for (int i = 0; i < 3; i++){ wAddr[i] += 64;  wr[i] = *(const sh8*)(wbf + wAddr[i]); }
        }
        __syncthreads();

        sh8 a0 = *(const sh8*)&pt[(wid*16 + lo)*72 + g*8];
        sh8 a1 = *(const sh8*)&pt[(wid*16 + lo)*72 + 32 + g*8];
        #pragma unroll
        for (int ct = 0; ct < 6; ct++){
            sh8 b0 = *(const sh8*)&wt[(ct*16 + lo)*72 + g*8];
            sh8 b1 = *(const sh8*)&wt[(ct*16 + lo)*72 + 32 + g*8];
            acc[ct] = __builtin_amdgcn_mfma_f32_16x16x32_bf16(a0, b0, acc[ct], 0, 0, 0);
            acc[ct] = __builtin_amdgcn_mfma_f32_16x16x32_bf16(a1, b1, acc[ct], 0, 0, 0);
        }
    }

    int rowsTotal = NB << posLog;
    #pragma unroll
    for (int ct = 0; ct < 6; ct++){
        int o = ct*16 + lo;
        #pragma unroll
        for (int jx = 0; jx < 4; jx++){
            int R = rb*64 + wid*16 + g*4 + jx;
            part[((size_t)split*rowsTotal + R)*96 + o] = acc[ct][jx];
        }
    }
}

// ---------------- 4. merged reduce (both branches): K-split sum + LN + gelu + Z/q/k -> bf16 ----------------
__global__ __launch_bounds__(64) void k_reduce(const float* __restrict__ part1,
                                               const float* __restrict__ part2,
                                               const float* __restrict__ cb1, const float* __restrict__ cb2,
                                               const float* __restrict__ lw1, const float* __restrict__ lw2,
                                               const float* __restrict__ lb1, const float* __restrict__ lb2,
                                               const float* __restrict__ wqk,
                                               const float* __restrict__ bqk,
                                               const float* __restrict__ g1, const float* __restrict__ g2,
                                               const float* __restrict__ be1, const float* __restrict__ be2,
                                               unsigned short* __restrict__ qp1, unsigned short* __restrict__ qp2,
                                               unsigned short* __restrict__ kt1, unsigned short* __restrict__ kt2){
    __shared__ float xsh[96];
    int bid = blockIdx.x;
    bool fst = bid < 1024;
    int row   = fst ? bid : bid - 1024;
    int nsplit= fst ? 32 : 8;
    int rows  = fst ? 1024 : 4096;
    int Mper  = fst ? 256 : 1024;
    const float* part = fst ? part1 : part2;
    const float* cbias= fst ? cb1 : cb2;
    const float* lw   = fst ? lw1 : lw2;
    const float* lb   = fst ? lb1 : lb2;
    const float* g    = fst ? g1 : g2;
    const float* be   = fst ? be1 : be2;
    unsigned short* qp = fst ? qp1 : qp2;
    unsigned short* ktp= fst ? kt1 : kt2;

    int l = threadIdx.x;
    float y1 = 0.0f, y2 = 0.0f;
    for (int s = 0; s < nsplit; s++){
        const float* pr = part + ((size_t)s*rows + row)*96;
        y1 += pr[l];
        if (l < 32) y2 += pr[64+l];
    }
    y1 += cbias[l];
    if (l < 32) y2 += cbias[64+l];
    float s = wave_sum64(y1 + ((l < 32) ? y2 : 0.0f));
    float m = s * (1.0f/96.0f);
    float d1 = y1 - m, d2 = y2 - m;
    float var = wave_sum64(d1*d1 + ((l < 32) ? d2*d2 : 0.0f)) * (1.0f/96.0f);
    float rstd = rsqrtf(var + EPSF);
    xsh[l] = geluf(d1*rstd*lw[l] + lb[l]);
    if (l < 32) xsh[64+l] = geluf(d2*rstd*lw[64+l] + lb[64+l]);
    __syncthreads();
    if (l < 48){
        float z = bqk[l];
        #pragma unroll 4
        for (int c = 0; c < 96; c++) z += xsh[c]*wqk[c*48 + l];
        z = siluf(z);
        float qv = (z*g[l]    + be[l]) * INV_N;   // fold 1/N into q
        float kv =  z*g[48+l] + be[48+l];
        int b = row / Mper, p = row - b*Mper;
        qp[(size_t)row*64 + l] = f2bf(qv);
        ktp[((size_t)b*48 + l)*Mper + p] = f2bf(kv);
    } else {
        qp[(size_t)row*64 + l] = 0;      // zero the d-pad
    }
}

// ---------------- 5. attention via bf16 MFMA: swapped QK^T + in-register P (permlane) ----------------
// Long blocks (M=1024) dispatched first for tail balance; V outputs stored bf16.
__global__ __launch_bounds__(256) void k_attn(const unsigned short* __restrict__ vbuf,
                                              const unsigned short* __restrict__ qp1,
                                              const unsigned short* __restrict__ ktp1,
                                              const unsigned short* __restrict__ qp2,
                                              const unsigned short* __restrict__ ktp2,
                                              unsigned short* __restrict__ V1,
                                              unsigned short* __restrict__ V2){
    __shared__ unsigned short qs[2][32*72];    // q[m][d] chunk, stride 72
    __shared__ unsigned short ks[2][48*72];    // kT[d][m] chunk, stride 72

    int bx   = blockIdx.x;
    int kind = (bx < 512) ? 1 : 0;      // long blocks first
    int blk  = (bx < 512) ? bx : bx - 512;
    int tid  = threadIdx.x;
    int wid  = tid >> 6;
    int lane = tid & 63;
    int lo   = lane & 15;
    int g    = lane >> 4;
    int row0 = blk*128 + wid*32;        // wave's first global row
    int b    = row0 >> 14;              // batch

    int   M    = kind ? 1024 : 256;
    const unsigned short* qp = (kind ? qp2 : qp1) + (size_t)b*M*64;
    const unsigned short* kt = (kind ? ktp2 : ktp1) + (size_t)b*48*M;
    int   voff = kind ? 48 : 0;
    unsigned short* vout = kind ? V2 : V1;

    // v B-fragments for 2 n-tiles: direct bf16 loads
    sh8 vb[2][2];
    #pragma unroll
    for (int nt = 0; nt < 2; nt++){
        const unsigned short* vrow = vbuf + (size_t)(row0 + nt*16 + lo)*CC + voff;
        vb[nt][0] = *(const sh8*)(vrow + g*8);
        if (g < 2) vb[nt][1] = *(const sh8*)(vrow + 32 + g*8);
        else { sh8 z = {0,0,0,0,0,0,0,0}; vb[nt][1] = z; }
    }

    int qm = tid >> 3, qj = tid & 7;
    int kd = tid >> 2, kj = tid & 3;
    bool kact = tid < 192;

    f32x4 acc[2][3];
    #pragma unroll
    for (int nt = 0; nt < 2; nt++)
        #pragma unroll
        for (int dt = 0; dt < 3; dt++) acc[nt][dt] = (f32x4){0.f,0.f,0.f,0.f};

    int nchunk = M >> 5;
    sh8 qreg = *(const sh8*)(qp + (size_t)qm*64 + qj*8);
    sh8 kreg;
    if (kact) kreg = *(const sh8*)(kt + (size_t)kd*M + kj*8);

    for (int ch = 0; ch < nchunk; ch++){
        int bs = ch & 1;
        unsigned short* qb = qs[bs];
        unsigned short* kb = ks[bs];
        *(sh8*)&qb[qm*72 + qj*8] = qreg;
        if (kact) *(sh8*)&kb[kd*72 + kj*8] = kreg;
        __syncthreads();                 // single barrier; dbuf handles WAR
        if (ch + 1 < nchunk){            // prefetch next chunk under compute
            int mb2 = (ch + 1)*32;
            qreg = *(const sh8*)(qp + (size_t)(mb2 + qm)*64 + qj*8);
            if (kact) kreg = *(const sh8*)(kt + (size_t)kd*M + mb2 + kj*8);
        }

        // ---- gemm1 (swapped): S^T tiles; q pre-scaled by 1/N ----
        sh8 aq[2][2];
        #pragma unroll
        for (int mt = 0; mt < 2; mt++)
            #pragma unroll
            for (int kc = 0; kc < 2; kc++)
                aq[mt][kc] = *(const sh8*)&qb[(mt*16 + lo)*72 + kc*32 + g*8];
        f32x4 c00, c01, c10, c11;
        c00 = (f32x4){0.f,0.f,0.f,0.f}; c01 = c00; c10 = c00; c11 = c00;
        c00 = __builtin_amdgcn_mfma_f32_16x16x32_bf16(aq[0][0], vb[0][0], c00, 0,0,0);
        c00 = __builtin_amdgcn_mfma_f32_16x16x32_bf16(aq[0][1], vb[0][1], c00, 0,0,0);
        c01 = __builtin_amdgcn_mfma_f32_16x16x32_bf16(aq[0][0], vb[1][0], c01, 0,0,0);
        c01 = __builtin_amdgcn_mfma_f32_16x16x32_bf16(aq[0][1], vb[1][1], c01, 0,0,0);
        c10 = __builtin_amdgcn_mfma_f32_16x16x32_bf16(aq[1][0], vb[0][0], c10, 0,0,0);
        c10 = __builtin_amdgcn_mfma_f32_16x16x32_bf16(aq[1][1], vb[0][1], c10, 0,0,0);
        c11 = __builtin_amdgcn_mfma_f32_16x16x32_bf16(aq[1][0], vb[1][0], c11, 0,0,0);
        c11 = __builtin_amdgcn_mfma_f32_16x16x32_bf16(aq[1][1], vb[1][1], c11, 0,0,0);

        // ---- P = relu(S)^2, cvt_pk, permlane redistribute -> pa[nt] ----
        sh8 pa[2];
        #pragma unroll
        for (int nt = 0; nt < 2; nt++){
            f32x4 cm0 = nt ? c01 : c00;
            f32x4 cm1 = nt ? c11 : c10;
            float p00 = fmaxf(cm0[0], 0.f); p00 *= p00;
            float p01 = fmaxf(cm0[1], 0.f); p01 *= p01;
            float p02 = fmaxf(cm0[2], 0.f); p02 *= p02;
            float p03 = fmaxf(cm0[3], 0.f); p03 *= p03;
            float p10 = fmaxf(cm1[0], 0.f); p10 *= p10;
            float p11 = fmaxf(cm1[1], 0.f); p11 *= p11;
            float p12 = fmaxf(cm1[2], 0.f); p12 *= p12;
            float p13 = fmaxf(cm1[3], 0.f); p13 *= p13;
            unsigned a0 = cvtpk(p00, p01);   // mt0, j01
            unsigned a1 = cvtpk(p02, p03);   // mt0, j23
            unsigned b0 = cvtpk(p10, p11);   // mt1, j01
            unsigned b1 = cvtpk(p12, p13);   // mt1, j23
            swap32(a0, b0); swap16(a0, b0);  // -> a0=W0, b0=W2
            swap32(a1, b1); swap16(a1, b1);  // -> a1=W1, b1=W3
            union { unsigned u[4]; sh8 v; } pk;
            pk.u[0] = a0; pk.u[1] = a1; pk.u[2] = b0; pk.u[3] = b1;
            pa[nt] = pk.v;
        }

        // ---- gemm2: acc[nt][dt] += P . k ----
        #pragma unroll
        for (int dt = 0; dt < 3; dt++){
            sh8 bk = *(const sh8*)&kb[(dt*16 + lo)*72 + g*8];
            acc[0][dt] = __builtin_amdgcn_mfma_f32_16x16x32_bf16(pa[0], bk, acc[0][dt], 0, 0, 0);
            acc[1][dt] = __builtin_amdgcn_mfma_f32_16x16x32_bf16(pa[1], bk, acc[1][dt], 0, 0, 0);
        }
    }

    // ---- write O bf16: row = row0 + nt*16 + g*4 + j, col = dt*16 + lo ----
    #pragma unroll
    for (int nt = 0; nt < 2; nt++)
        #pragma unroll
        for (int dt = 0; dt < 3; dt++)
            #pragma unroll
            for (int j = 0; j < 4; j++)
                vout[(size_t)(row0 + nt*16 + g*4 + j)*48 + dt*16 + lo] =
                    (unsigned short)cvtpk(acc[nt][dt][j], acc[nt][dt][j]);
}

// ---------------- 6. final via bf16 MFMA: out = (xc*gate)@proj + projb + xc ----------------
__global__ __launch_bounds__(256) void k_final(const unsigned short* __restrict__ V1,
                                               const unsigned short* __restrict__ V2,
                                               const unsigned short* __restrict__ gate,
                                               const float* __restrict__ projw,
                                               const float* __restrict__ projb,
                                               float* __restrict__ out){
    __shared__ unsigned short pjbf[96*100];    // [col][k] bf16, stride 100
    int tid  = threadIdx.x;
    int lane = tid & 63;
    int wid  = tid >> 6;
    int lo   = lane & 15;
    int g    = lane >> 4;
    int row0 = blockIdx.x*64 + wid*16;

    // stage proj_w via paired cvt_pk: 4608 col-pairs over [96k][48 colpair]
    #pragma unroll
    for (int it = 0; it < 18; it++){
        int pidx = tid + it*256;
        int k = pidx / 48, cp = (pidx - k*48)*2;
        float2 v = *(const float2*)&projw[k*CC + cp];
        unsigned u = cvtpk(v.x, v.y);
        pjbf[cp*100 + k]     = (unsigned short)u;
        pjbf[(cp+1)*100 + k] = (unsigned short)(u >> 16);
    }

    // A-fragments: value = xc*gate from bf16 sources
    sh8 a[3];
    {
        size_t row = row0 + lo;
        const unsigned short* gr = gate + row*CC;
        #pragma unroll
        for (int kc = 0; kc < 3; kc++){
            int d0 = kc*32 + g*8;
            const unsigned short* xsrc = (d0 < 48) ? (V1 + row*48 + d0) : (V2 + row*48 + d0 - 48);
            union { sh8 v; unsigned u[4]; } xu, gu, pk;
            xu.v = *(const sh8*)xsrc;
            gu.v = *(const sh8*)(gr + d0);
            #pragma unroll
            for (int i = 0; i < 4; i++){
                float xl = b2f(xu.u[i] << 16),        xh = b2f(xu.u[i] & 0xffff0000u);
                float gl = b2f(gu.u[i] << 16),        gh = b2f(gu.u[i] & 0xffff0000u);
                pk.u[i] = cvtpk(xl*gl, xh*gh);
            }
            a[kc] = pk.v;
        }
    }
    __syncthreads();

    f32x4 acc[6];
    #pragma unroll
    for (int ct = 0; ct < 6; ct++) acc[ct] = (f32x4){0.f,0.f,0.f,0.f};
    #pragma unroll
    for (int ct = 0; ct < 6; ct++){
        #pragma unroll
        for (int kc = 0; kc < 3; kc++){
            sh8 bw = *(const sh8*)&pjbf[(ct*16 + lo)*100 + kc*32 + g*8];
            acc[ct] = __builtin_amdgcn_mfma_f32_16x16x32_bf16(a[kc], bw, acc[ct], 0, 0, 0);
        }
    }

    #pragma unroll
    for (int ct = 0; ct < 6; ct++){
        int col = ct*16 + lo;
        float bcol = projb[col];
        const unsigned short* xsrc = (ct < 3) ? (V1 + col) : (V2 + col - 48);
        #pragma unroll
        for (int j = 0; j < 4; j++){
            size_t row = row0 + g*4 + j;
            float xc = b2f((unsigned)xsrc[row*48] << 16);
            out[row*CC + col] = acc[ct][j] + bcol + xc;
        }
    }
}

extern "C" void kernel_launch(void* const* d_in, const int* in_sizes, int n_in,
                              void* d_out, int out_size, void* d_ws, size_t ws_size,
                              hipStream_t stream){
    const float* x      = (const float*)d_in[0];
    const float* norm_w = (const float*)d_in[3];
    const float* norm_b = (const float*)d_in[4];
    const float* Wh     = (const float*)d_in[5];
    const float* bh     = (const float*)d_in[6];
    const float* Wqk    = (const float*)d_in[7];
    const float* bqk    = (const float*)d_in[8];
    const float* g1     = (const float*)d_in[9];
    const float* be1    = (const float*)d_in[10];
    const float* g2     = (const float*)d_in[11];
    const float* be2    = (const float*)d_in[12];
    const float* sr1_w  = (const float*)d_in[13];
    const float* sr1_b  = (const float*)d_in[14];
    const float* sr2_w  = (const float*)d_in[15];
    const float* sr2_b  = (const float*)d_in[16];
    const float* n1_w   = (const float*)d_in[17];
    const float* n1_b   = (const float*)d_in[18];
    const float* n2_w   = (const float*)d_in[19];
    const float* n2_b   = (const float*)d_in[20];
    const float* proj_w = (const float*)d_in[21];
    const float* proj_b = (const float*)d_in[22];
    float* out = (float*)d_out;

    float* ws = (float*)d_ws;
    size_t off = 0;
    unsigned short* nxbf = (unsigned short*)(ws + off); off += (size_t)NB*NTOK*CC/2;
    unsigned short* nxim = (unsigned short*)(ws + off); off += (size_t)NB*NTOK*CC/2;
    unsigned short* w1bf = (unsigned short*)(ws + off); off += (size_t)96*6144/2;
    unsigned short* w2bf = (unsigned short*)(ws + off); off += (size_t)96*1536/2;
    unsigned short* vbuf = (unsigned short*)(ws + off); off += (size_t)NB*NTOK*CC/2;
    unsigned short* gate = (unsigned short*)(ws + off); off += (size_t)NB*NTOK*CC/2;
    unsigned short* qp1 = (unsigned short*)(ws + off); off += (size_t)NB*256*64/2;
    unsigned short* kt1 = (unsigned short*)(ws + off); off += (size_t)NB*48*256/2;
    unsigned short* qp2 = (unsigned short*)(ws + off); off += (size_t)NB*1024*64/2;
    unsigned short* kt2 = (unsigned short*)(ws + off); off += (size_t)NB*48*1024/2;
    float* part1= ws + off; off += (size_t)32*NB*256*96;
    float* part2= ws + off; off += (size_t)8*NB*1024*96;
    unsigned short* V1 = (unsigned short*)(ws + off); off += (size_t)NB*NTOK*48/2;
    unsigned short* V2 = (unsigned short*)(ws + off); off += (size_t)NB*NTOK*48/2;
    if (ws_size < off*sizeof(float)) return;

    k_ln   <<<17104, 256, 0, stream>>>(x, norm_w, norm_b, nxbf, nxim,
                                       sr1_w, w1bf, 96*6144, sr2_w, w2bf, 96*1536);
    k_hgemm<<<1024, 256, 0, stream>>>(nxbf, Wh, bh, vbuf, gate);
    k_conv <<<512, 256, 0, stream>>>(nxim, w1bf, part1, 8, 4, 3, 6144, 16);
    k_conv <<<512, 256, 0, stream>>>(nxim, w2bf, part2, 10, 5, 2, 1536, 64);
    k_reduce<<<5120, 64, 0, stream>>>(part1, part2, sr1_b, sr2_b, n1_w, n2_w, n1_b, n2_b,
                                      Wqk, bqk, g1, g2, be1, be2, qp1, qp2, kt1, kt2);
    k_attn <<<1024, 256, 0, stream>>>(vbuf, qp1, kt1, qp2, kt2, V1, V2);
    k_final<<<1024, 256, 0, stream>>>(V1, V2, gate, proj_w, proj_b, out);
}